// Round 7
// baseline (534.411 us; speedup 1.0000x reference)
//
#include <hip/hip_runtime.h>
#include <math.h>

#define SEQ  1024
#define DIM  256
#define WIN  10

typedef __attribute__((ext_vector_type(8))) short  short8;
typedef __attribute__((ext_vector_type(4))) float  f32x4;

static __device__ __forceinline__ float bf2f(ushort u) {
    unsigned v = ((unsigned)u) << 16;
    return __builtin_bit_cast(float, v);
}
static __device__ __forceinline__ ushort f2bf(float f) {
    unsigned x = __builtin_bit_cast(unsigned, f);
    unsigned r = x + 0x7fffu + ((x >> 16) & 1u);
    return (ushort)(r >> 16);
}
static __device__ __forceinline__ int comp(int4 v, int i) {
    switch (i & 3) { case 0: return v.x; case 1: return v.y;
                     case 2: return v.z; default: return v.w; }
}
static __device__ __forceinline__ void gld16(const ushort* g, ushort* l) {
    __builtin_amdgcn_global_load_lds(
        (const __attribute__((address_space(1))) void*)g,
        (__attribute__((address_space(3))) void*)l, 16, 0, 0);
}

// ---------------------------------------------------------------------------
// fp32 [z][K][N] -> bf16 [z][N][K] transposes
// ---------------------------------------------------------------------------
__global__ __launch_bounds__(256) void transpose_bf16(
    const float* __restrict__ in, ushort* __restrict__ out, int K, int N)
{
    __shared__ float tile[32][33];
    const float* W = in + (size_t)blockIdx.z * K * N;
    ushort* O = out + (size_t)blockIdx.z * K * N;
    int n0 = blockIdx.x * 32, k0 = blockIdx.y * 32;
    int tx = threadIdx.x & 31, ty = threadIdx.x >> 5;
#pragma unroll
    for (int r = 0; r < 32; r += 8)
        tile[ty + r][tx] = W[(size_t)(k0 + ty + r) * N + n0 + tx];
    __syncthreads();
#pragma unroll
    for (int r = 0; r < 32; r += 8)
        O[(size_t)(n0 + ty + r) * K + k0 + tx] = f2bf(tile[tx][ty + r]);
}

// Merged transpose for the 35 attention 256x256 weights (5 groups x 7 mods).
__global__ __launch_bounds__(256) void transpose_qkv(
    const float* __restrict__ Wq, const float* __restrict__ Wk,
    const float* __restrict__ Wv, const float* __restrict__ Gw,
    const float* __restrict__ Ow, ushort* __restrict__ out)
{
    __shared__ float tile[32][33];
    int z = blockIdx.z;
    const float* base = (z < 7) ? Wq : (z < 14) ? Wk : (z < 21) ? Wv
                       : (z < 28) ? Gw : Ow;
    const float* W = base + (size_t)(z % 7) * 65536;
    ushort* O = out + (size_t)z * 65536;
    int n0 = blockIdx.x * 32, k0 = blockIdx.y * 32;
    int tx = threadIdx.x & 31, ty = threadIdx.x >> 5;
#pragma unroll
    for (int r = 0; r < 32; r += 8)
        tile[ty + r][tx] = W[(size_t)(k0 + ty + r) * 256 + n0 + tx];
    __syncthreads();
#pragma unroll
    for (int r = 0; r < 32; r += 8)
        O[(size_t)(n0 + ty + r) * 256 + k0 + tx] = f2bf(tile[tx][ty + r]);
}

// ---------------------------------------------------------------------------
// Batched LayerNorm: 4 rows/block (one per wave). Module by LOCAL row chunk.
// ---------------------------------------------------------------------------
__global__ __launch_bounds__(256) void ln_bat(
    const float* __restrict__ x, ushort* __restrict__ dst,
    const float* __restrict__ g, const float* __restrict__ b,
    int rowOff, int4 mods)
{
    int wave = threadIdx.x >> 6, lane = threadIdx.x & 63;
    int lrow = blockIdx.x * 4 + wave;
    int gr   = rowOff + lrow;
    int mod  = comp(mods, lrow >> 11);

    float4 v = ((const float4*)(x + (size_t)gr * 256))[lane];
    float s  = v.x + v.y + v.z + v.w;
    float sq = v.x * v.x + v.y * v.y + v.z * v.z + v.w * v.w;
#pragma unroll
    for (int off = 1; off <= 32; off <<= 1) {
        s  += __shfl_xor(s, off);
        sq += __shfl_xor(sq, off);
    }
    float mean = s * (1.0f / 256.0f);
    float var  = sq * (1.0f / 256.0f) - mean * mean;
    float rstd = rsqrtf(var + 1e-5f);

    float4 g4 = ((const float4*)(g + mod * 256))[lane];
    float4 b4 = ((const float4*)(b + mod * 256))[lane];
    ushort4 o;
    o.x = f2bf((v.x - mean) * rstd * g4.x + b4.x);
    o.y = f2bf((v.y - mean) * rstd * g4.y + b4.y);
    o.z = f2bf((v.z - mean) * rstd * g4.z + b4.z);
    o.w = f2bf((v.w - mean) * rstd * g4.w + b4.w);
    *(ushort4*)(dst + (size_t)gr * 256 + lane * 4) = o;
}

// Streaming staging: NR rows x 64 cols, granule swizzle cg = (lane&7)^r8.
template<int NR>
static __device__ __forceinline__ void stage(
    const ushort* src, int stride, ushort* lds, int wave, int lane)
{
    int r8 = lane >> 3;
    int cg = (lane & 7) ^ r8;
    const int NCH = NR / 8;
#pragma unroll
    for (int ii = 0; ii < NCH / 4; ++ii) {
        int ci = wave + ii * 4;
        gld16(src + (size_t)(ci * 8 + r8) * stride + cg * 8, lds + ci * 512);
    }
}

// ---------------------------------------------------------------------------
// Streaming BK=64 GEMM core (THE proven shape: 12 KB LDS at FM=1/FN=2 ->
// 4-8 resident blocks/CU; latency hidden by block TLP, not by pipeline).
// ---------------------------------------------------------------------------
template<int FM, int FN>
static __device__ __forceinline__ void mfma_core(
    const ushort* __restrict__ A, const ushort* __restrict__ B,
    int Kloop, int sA, int sB, ushort* As, ushort* Bs, f32x4 acc[FM][FN])
{
    int tid = threadIdx.x, wave = tid >> 6, lane = tid & 63;
    int wr = wave >> 1, wc = wave & 1, lr = lane & 15, q = lane >> 4;
    for (int k0 = 0; k0 < Kloop; k0 += 64) {
        stage<32 * FM>(A + k0, sA, As, wave, lane);
        stage<32 * FN>(B + k0, sB, Bs, wave, lane);
        __syncthreads();
        short8 af[2][FM], bf_[2][FN];
#pragma unroll
        for (int s = 0; s < 2; ++s) {
#pragma unroll
            for (int fm = 0; fm < FM; ++fm) {
                int row = (wr * FM + fm) * 16 + lr;
                af[s][fm] = *(const short8*)(As + row * 64 + ((s * 4 + q) ^ (row & 7)) * 8);
            }
#pragma unroll
            for (int fn = 0; fn < FN; ++fn) {
                int row = (wc * FN + fn) * 16 + lr;
                bf_[s][fn] = *(const short8*)(Bs + row * 64 + ((s * 4 + q) ^ (row & 7)) * 8);
            }
        }
#pragma unroll
        for (int s = 0; s < 2; ++s)
#pragma unroll
            for (int fm = 0; fm < FM; ++fm)
#pragma unroll
                for (int fn = 0; fn < FN; ++fn)
                    acc[fm][fn] = __builtin_amdgcn_mfma_f32_16x16x32_bf16(
                        af[s][fm], bf_[s][fn], acc[fm][fn], 0, 0, 0);
        __syncthreads();
    }
}

// ---------------------------------------------------------------------------
// Split-K streaming GEMM (FF2), fp32 atomicAdd epilogue (residual in outf).
// ---------------------------------------------------------------------------
template<int FM, int FN>
__global__ __launch_bounds__(256) void gemm_split(
    const ushort* __restrict__ A, const ushort* __restrict__ Wt,
    const float* __restrict__ bias, float* __restrict__ outf,
    int N, int Ktot, int Kseg, int4 mods)
{
    __shared__ __align__(16) ushort As[32 * FM * 64];
    __shared__ __align__(16) ushort Bs[32 * FN * 64];
    f32x4 acc[FM][FN];
#pragma unroll
    for (int i = 0; i < FM; ++i)
#pragma unroll
        for (int j = 0; j < FN; ++j) acc[i][j] = (f32x4){0.f, 0.f, 0.f, 0.f};

    int bm = blockIdx.x * 32 * FM, bn = blockIdx.y * 32 * FN, bz = blockIdx.z;
    int mod = comp(mods, bm >> 11);
    mfma_core<FM, FN>(A + (size_t)bm * Ktot + bz * Kseg,
                      Wt + (size_t)mod * N * Ktot + (size_t)bn * Ktot + bz * Kseg,
                      Kseg, Ktot, Ktot, As, Bs, acc);

    int wave = threadIdx.x >> 6, lane = threadIdx.x & 63;
    int wr = wave >> 1, wc = wave & 1, lr = lane & 15, q = lane >> 4;
#pragma unroll
    for (int fm = 0; fm < FM; ++fm) {
#pragma unroll
        for (int rr = 0; rr < 4; ++rr) {
            int row = bm + (wr * FM + fm) * 16 + q * 4 + rr;
#pragma unroll
            for (int fn = 0; fn < FN; ++fn) {
                int col = bn + (wc * FN + fn) * 16 + lr;
                float v = acc[fm][fn][rr];
                if (bz == 0) v += bias[mod * N + col];
                atomicAdd(outf + (size_t)row * N + col, v);
            }
        }
    }
}

// ---------------------------------------------------------------------------
// Streaming QKVG projection, 32x64 tile, 12 KB LDS.
// grid (rows/32, 16): sect = y>>2, bn = (y&3)*64.
// Q/K/G -> big[row][1024] sections 0,1,3.  V -> vt[chunk][h][ch][row].
// ---------------------------------------------------------------------------
__global__ __launch_bounds__(256) void qkvg_st(
    const ushort* __restrict__ t, const ushort* __restrict__ wT,
    const float* __restrict__ gb, ushort* __restrict__ big,
    ushort* __restrict__ vt, int4 qoff, int4 kvoff, int4 wmods)
{
    __shared__ __align__(16) ushort As[32 * 64];   // 4 KB
    __shared__ __align__(16) ushort Bs[64 * 64];   // 8 KB

    int bm = blockIdx.x * 32;
    int sect = blockIdx.y >> 2, bn = (blockIdx.y & 3) * 64;
    int chunk = bm >> 11, lrow = bm & 2047;
    int wmod = comp(wmods, chunk);
    int asrc = ((sect == 0) ? comp(qoff, chunk) : comp(kvoff, chunk)) + lrow;

    f32x4 acc[1][2];
    acc[0][0] = (f32x4){0.f, 0.f, 0.f, 0.f};
    acc[0][1] = (f32x4){0.f, 0.f, 0.f, 0.f};
    mfma_core<1, 2>(t + (size_t)asrc * 256,
                    wT + (size_t)(sect * 7 + wmod) * 65536 + (size_t)bn * 256,
                    256, 256, 256, As, Bs, acc);

    int wave = threadIdx.x >> 6, lane = threadIdx.x & 63;
    int wr = wave >> 1, wc = wave & 1, lr = lane & 15, q = lane >> 4;
    if (sect == 2) {
#pragma unroll
        for (int fn = 0; fn < 2; ++fn) {
            int col = bn + (wc * 2 + fn) * 16 + lr;
            int hh = col >> 6, ch = col & 63;
            int row0 = lrow + wr * 16 + q * 4;
            ushort4 w;
            w.x = f2bf(acc[0][fn][0]); w.y = f2bf(acc[0][fn][1]);
            w.z = f2bf(acc[0][fn][2]); w.w = f2bf(acc[0][fn][3]);
            *(ushort4*)(vt + ((size_t)((chunk * 4 + hh) * 64 + ch)) * 2048 + row0) = w;
        }
    } else {
#pragma unroll
        for (int rr = 0; rr < 4; ++rr) {
            int rloc = wr * 16 + q * 4 + rr;
#pragma unroll
            for (int fn = 0; fn < 2; ++fn) {
                int col = bn + (wc * 2 + fn) * 16 + lr;
                float v = acc[0][fn][rr];
                if (sect == 3) v = 1.0f / (1.0f + __expf(-(v + gb[wmod * 256 + col])));
                big[(size_t)(chunk * 2048 + lrow + rloc) * 1024 + sect * 256 + col] = f2bf(v);
            }
        }
    }
}

// ---------------------------------------------------------------------------
// Streaming FF up-proj, 32x64 tile, 12 KB LDS. grid (rows/32, 32).
// ---------------------------------------------------------------------------
__global__ __launch_bounds__(256) void ff1_st(
    const ushort* __restrict__ t, const ushort* __restrict__ W1,
    const float* __restrict__ fb1, ushort* __restrict__ outb, int4 fmods)
{
    __shared__ __align__(16) ushort As[32 * 64];   // 4 KB
    __shared__ __align__(16) ushort Bs[64 * 64];   // 8 KB

    int bm = blockIdx.x * 32, bn = blockIdx.y * 64;
    int mod = comp(fmods, bm >> 11);

    f32x4 acc[1][2];
    acc[0][0] = (f32x4){0.f, 0.f, 0.f, 0.f};
    acc[0][1] = (f32x4){0.f, 0.f, 0.f, 0.f};
    mfma_core<1, 2>(t + (size_t)bm * 256,
                    W1 + (size_t)mod * 524288 + (size_t)bn * 256,
                    256, 256, 256, As, Bs, acc);

    int wave = threadIdx.x >> 6, lane = threadIdx.x & 63;
    int wr = wave >> 1, wc = wave & 1, lr = lane & 15, q = lane >> 4;
#pragma unroll
    for (int rr = 0; rr < 4; ++rr) {
        int row = bm + wr * 16 + q * 4 + rr;
#pragma unroll
        for (int fn = 0; fn < 2; ++fn) {
            int col = bn + (wc * 2 + fn) * 16 + lr;
            float v = acc[0][fn][rr] + fb1[mod * 2048 + col];
            outb[(size_t)row * 2048 + col] = f2bf(fmaxf(v, 0.0f));
        }
    }
}

// ---------------------------------------------------------------------------
// Banded attention core: ONE 64-thread block per (16-query tile, head).
// grid (ntiles, 4). No inter-wave barriers; lsum stays in registers.
// Writes gated, 1/l-scaled attention output (pre-oproj) to abuf[row][256].
// Math identical to the verified attn_op QK^T/softmax/PV path.
// ---------------------------------------------------------------------------
__global__ __launch_bounds__(64) void attn_st(
    const ushort* __restrict__ big, const ushort* __restrict__ vt,
    ushort* __restrict__ abuf)
{
    __shared__ __align__(16) ushort P[16 * 72];   // 2.25 KB

    int tile = blockIdx.x, h = blockIdx.y;
    int chunk = tile >> 7, lt = tile & 127;
    int r0 = lt * 16, s0 = r0 & 1023, seqb = r0 & 1024;
    int t0 = s0 - 16; t0 = t0 < 0 ? 0 : (t0 > SEQ - 48 ? SEQ - 48 : t0);
    int lane = threadIdx.x;
    int lr = lane & 15, q = lane >> 4;
    size_t rowbase = (size_t)(chunk * 2048 + r0);
    size_t kvbase  = (size_t)(chunk * 2048 + seqb + t0);

    // S = Q K^T
    short8 aq[2];
#pragma unroll
    for (int s = 0; s < 2; ++s)
        aq[s] = *(const short8*)(big + (rowbase + lr) * 1024 + h * 64 + s * 32 + q * 8);
    f32x4 sc[3];
#pragma unroll
    for (int kt = 0; kt < 3; ++kt) {
        sc[kt] = (f32x4){0.f, 0.f, 0.f, 0.f};
        const ushort* kr = big + (kvbase + kt * 16 + lr) * 1024 + 256 + h * 64;
#pragma unroll
        for (int s = 0; s < 2; ++s)
            sc[kt] = __builtin_amdgcn_mfma_f32_16x16x32_bf16(
                aq[s], *(const short8*)(kr + s * 32 + q * 8), sc[kt], 0, 0, 0);
    }
    // zero P pad cols 48..63
    { int zr = lane >> 2, zc = 48 + (lane & 3) * 4;
      *(ushort4*)(P + zr * 72 + zc) = (ushort4){0, 0, 0, 0}; }
    // mask + softmax (rows=queries, cols=keys); lsum uniform in lr-group
    float pv[3][4], lsum[4];
#pragma unroll
    for (int r = 0; r < 4; ++r) {
        int sq = s0 + q * 4 + r;
#pragma unroll
        for (int kt = 0; kt < 3; ++kt) {
            int tt = t0 + kt * 16 + lr;
            int d = tt - sq;
            pv[kt][r] = (d <= WIN && d >= -WIN) ? sc[kt][r] * 0.125f : -1e30f;
        }
        float m = fmaxf(pv[0][r], fmaxf(pv[1][r], pv[2][r]));
#pragma unroll
        for (int off = 1; off <= 8; off <<= 1) m = fmaxf(m, __shfl_xor(m, off));
        float l = 0.f;
#pragma unroll
        for (int kt = 0; kt < 3; ++kt) { float p = __expf(pv[kt][r] - m); pv[kt][r] = p; l += p; }
#pragma unroll
        for (int off = 1; off <= 8; off <<= 1) l += __shfl_xor(l, off);
        lsum[r] = l;
    }
#pragma unroll
    for (int r = 0; r < 4; ++r)
#pragma unroll
        for (int kt = 0; kt < 3; ++kt)
            P[(q * 4 + r) * 72 + kt * 16 + lr] = f2bf(pv[kt][r]);
    __syncthreads();   // single wave: effectively a waitcnt

    // O = P @ V; apply 1/l and G; store bf16 to abuf[row][ch]
#pragma unroll
    for (int ct = 0; ct < 4; ++ct) {
        f32x4 o = (f32x4){0.f, 0.f, 0.f, 0.f};
#pragma unroll
        for (int s = 0; s < 2; ++s) {
            short8 av = *(const short8*)(vt +
                ((size_t)((chunk * 4 + h) * 64 + ct * 16 + lr)) * 2048 +
                seqb + t0 + s * 32 + q * 8);
            short8 bp = *(const short8*)(P + lr * 72 + s * 32 + q * 8);
            o = __builtin_amdgcn_mfma_f32_16x16x32_bf16(bp, av, o, 0, 0, 0);
        }
        int ch = h * 64 + ct * 16 + lr;
#pragma unroll
        for (int r = 0; r < 4; ++r) {
            int qr = q * 4 + r;
            float gv = bf2f(big[(rowbase + qr) * 1024 + 768 + ch]);
            float val = o[r] * (1.0f / lsum[r]) * gv;
            abuf[(rowbase + qr) * 256 + ch] = f2bf(val);
        }
    }
}

// ---------------------------------------------------------------------------
// O-projection as streaming GEMM (proven shape): X += abuf @ Wo^T + bias.
// grid (rows/32, 4). atomicAdd (phase C: two modules add into same O rows).
// ---------------------------------------------------------------------------
__global__ __launch_bounds__(256) void oproj_st(
    const ushort* __restrict__ abuf, const ushort* __restrict__ woT,
    const float* __restrict__ aOb, float* __restrict__ X,
    int4 orow, int4 wmods)
{
    __shared__ __align__(16) ushort As[32 * 64];   // 4 KB
    __shared__ __align__(16) ushort Bs[64 * 64];   // 8 KB

    int bm = blockIdx.x * 32, bn = blockIdx.y * 64;
    int chunk = bm >> 11, lrow = bm & 2047;
    int mod = comp(wmods, chunk);

    f32x4 acc[1][2];
    acc[0][0] = (f32x4){0.f, 0.f, 0.f, 0.f};
    acc[0][1] = (f32x4){0.f, 0.f, 0.f, 0.f};
    mfma_core<1, 2>(abuf + (size_t)bm * 256,
                    woT + (size_t)mod * 65536 + (size_t)bn * 256,
                    256, 256, 256, As, Bs, acc);

    int wave = threadIdx.x >> 6, lane = threadIdx.x & 63;
    int wr = wave >> 1, wc = wave & 1, lr = lane & 15, q = lane >> 4;
    int xrow0 = comp(orow, chunk) + lrow;
#pragma unroll
    for (int rr = 0; rr < 4; ++rr) {
        int row = xrow0 + wr * 16 + q * 4 + rr;
#pragma unroll
        for (int fn = 0; fn < 2; ++fn) {
            int col = bn + (wc * 2 + fn) * 16 + lr;
            atomicAdd(X + (size_t)row * 256 + col,
                      acc[0][fn][rr] + aOb[mod * 256 + col]);
        }
    }
}

// ---------------------------------------------------------------------------
// Orchestration
// ---------------------------------------------------------------------------
extern "C" void kernel_launch(void* const* d_in, const int* in_sizes, int n_in,
                              void* d_out, int out_size, void* d_ws, size_t ws_size,
                              hipStream_t stream)
{
    const float* inL   = (const float*)d_in[0];
    const float* inN   = (const float*)d_in[1];
    const float* inO   = (const float*)d_in[2];
    const float* aWq   = (const float*)d_in[4];
    const float* aWk   = (const float*)d_in[5];
    const float* aWv   = (const float*)d_in[6];
    const float* aGw   = (const float*)d_in[7];
    const float* aGb   = (const float*)d_in[8];
    const float* aOw   = (const float*)d_in[9];
    const float* aOb   = (const float*)d_in[10];
    const float* ln_g  = (const float*)d_in[11];
    const float* ln_b  = (const float*)d_in[12];
    const float* ff_g  = (const float*)d_in[13];
    const float* ff_b  = (const float*)d_in[14];
    const float* ff_w1 = (const float*)d_in[15];
    const float* ff_b1 = (const float*)d_in[16];
    const float* ff_w2 = (const float*)d_in[17];
    const float* ff_b2 = (const float*)d_in[18];

    const size_t TD = (size_t)2048 * DIM;
    float* X = (float*)d_out;               // [6144][256]: L | N | O

    ushort* ws   = (ushort*)d_ws;
    ushort* wT   = ws;                      // 35 x 65536 (q0..6,k,v,g,o)
    ushort* woT  = wT + 28 * 65536;         // o-proj weights (within wT)
    ushort* w1T  = wT + 35 * 65536;         // 6x [2048][256]
    ushort* w2T  = w1T + 6 * 524288;        // 6x [256][2048]
    ushort* t    = w2T + 6 * 524288;        // [6144][256] LN outputs
    ushort* big  = t + 6144 * 256;          // QKVG [6144][1024] / FF hidden
    ushort* vt   = big + (size_t)6144 * 2048; // V^T: 3 chunks x 4h x 64ch x 2048
    ushort* abuf = vt + (size_t)12 * 64 * 2048; // attn out [6144][256]

    transpose_qkv<<<dim3(8, 8, 35), 256, 0, stream>>>(aWq, aWk, aWv, aGw, aOw, wT);
    transpose_bf16<<<dim3(64, 8, 6), 256, 0, stream>>>(ff_w1, w1T, 256, 2048);
    transpose_bf16<<<dim3(8, 64, 6), 256, 0, stream>>>(ff_w2, w2T, 2048, 256);

    hipMemcpyAsync(X,          inL, TD * sizeof(float), hipMemcpyDeviceToDevice, stream);
    hipMemcpyAsync(X + TD,     inN, TD * sizeof(float), hipMemcpyDeviceToDevice, stream);
    hipMemcpyAsync(X + 2 * TD, inO, TD * sizeof(float), hipMemcpyDeviceToDevice, stream);

    auto ffblock = [&](int nrows, int rowOff, int4 fmods) {
        ln_bat<<<dim3(nrows / 4), 256, 0, stream>>>(X, t, ff_g, ff_b, rowOff, fmods);
        ff1_st<<<dim3(nrows / 32, 32), 256, 0, stream>>>(
            t + (size_t)rowOff * 256, w1T, ff_b1, big, fmods);
        gemm_split<1, 2><<<dim3(nrows / 32, 4, 4), 256, 0, stream>>>(
            big, w2T, ff_b2, X + (size_t)rowOff * 256, 256, 2048, 512, fmods);
    };

    for (int it = 0; it < 2; ++it) {
        // ---- Phase A: self-attention + FF on L,N,O (mods 0,1,2) ----
        ln_bat<<<dim3(1536), 256, 0, stream>>>(X, t, ln_g, ln_b, 0, make_int4(0, 1, 2, 0));
        qkvg_st<<<dim3(192, 16), 256, 0, stream>>>(
            t, wT, aGb, big, vt,
            make_int4(0, 2048, 4096, 0), make_int4(0, 2048, 4096, 0),
            make_int4(0, 1, 2, 0));
        attn_st<<<dim3(384, 4), 64, 0, stream>>>(big, vt, abuf);
        oproj_st<<<dim3(192, 4), 256, 0, stream>>>(
            abuf, woT, aOb, X, make_int4(0, 2048, 4096, 0), make_int4(0, 1, 2, 0));
        ffblock(6144, 0, make_int4(0, 1, 2, 0));

        // ---- Phase B: L,N cross-attend tO (mods 3,4; ln by src chunk 4,5,3) ----
        ln_bat<<<dim3(1536), 256, 0, stream>>>(X, t, ln_g, ln_b, 0, make_int4(4, 5, 3, 0));
        qkvg_st<<<dim3(128, 16), 256, 0, stream>>>(
            t, wT, aGb, big, vt,
            make_int4(0, 2048, 0, 0), make_int4(4096, 4096, 0, 0),
            make_int4(3, 4, 0, 0));
        attn_st<<<dim3(256, 4), 64, 0, stream>>>(big, vt, abuf);
        oproj_st<<<dim3(128, 4), 256, 0, stream>>>(
            abuf, woT, aOb, X, make_int4(0, 2048, 0, 0), make_int4(3, 4, 0, 0));
        ffblock(4096, 0, make_int4(3, 4, 0, 0));

        // ---- Phase C: O += att5(tO,tN) + att6(tO,tL); FF(5,O) ----
        ln_bat<<<dim3(1536), 256, 0, stream>>>(X, t, ln_g, ln_b, 0, make_int4(6, 7, 8, 0));
        qkvg_st<<<dim3(128, 16), 256, 0, stream>>>(
            t, wT, aGb, big, vt,
            make_int4(4096, 4096, 0, 0), make_int4(2048, 0, 0, 0),
            make_int4(5, 6, 0, 0));
        attn_st<<<dim3(256, 4), 64, 0, stream>>>(big, vt, abuf);
        // both chunks project into the same O rows (atomicAdd); biases 5+6 both added
        oproj_st<<<dim3(128, 4), 256, 0, stream>>>(
            abuf, woT, aOb, X, make_int4(4096, 4096, 0, 0), make_int4(5, 6, 0, 0));
        ffblock(2048, 4096, make_int4(5, 0, 0, 0));
    }
}

// Round 8
// 495.479 us; speedup vs baseline: 1.0786x; 1.0786x over previous
//
#include <hip/hip_runtime.h>
#include <math.h>

#define SEQ  1024
#define DIM  256
#define WIN  10

typedef __attribute__((ext_vector_type(8))) short  short8;
typedef __attribute__((ext_vector_type(4))) float  f32x4;

static __device__ __forceinline__ float bf2f(ushort u) {
    unsigned v = ((unsigned)u) << 16;
    return __builtin_bit_cast(float, v);
}
static __device__ __forceinline__ ushort f2bf(float f) {
    unsigned x = __builtin_bit_cast(unsigned, f);
    unsigned r = x + 0x7fffu + ((x >> 16) & 1u);
    return (ushort)(r >> 16);
}
static __device__ __forceinline__ int comp(int4 v, int i) {
    switch (i & 3) { case 0: return v.x; case 1: return v.y;
                     case 2: return v.z; default: return v.w; }
}
static __device__ __forceinline__ void gld16(const ushort* g, ushort* l) {
    __builtin_amdgcn_global_load_lds(
        (const __attribute__((address_space(1))) void*)g,
        (__attribute__((address_space(3))) void*)l, 16, 0, 0);
}

// ---------------------------------------------------------------------------
// fp32 [z][K][N] -> bf16 [z][N][K] transposes
// ---------------------------------------------------------------------------
__global__ __launch_bounds__(256) void transpose_bf16(
    const float* __restrict__ in, ushort* __restrict__ out, int K, int N)
{
    __shared__ float tile[32][33];
    const float* W = in + (size_t)blockIdx.z * K * N;
    ushort* O = out + (size_t)blockIdx.z * K * N;
    int n0 = blockIdx.x * 32, k0 = blockIdx.y * 32;
    int tx = threadIdx.x & 31, ty = threadIdx.x >> 5;
#pragma unroll
    for (int r = 0; r < 32; r += 8)
        tile[ty + r][tx] = W[(size_t)(k0 + ty + r) * N + n0 + tx];
    __syncthreads();
#pragma unroll
    for (int r = 0; r < 32; r += 8)
        O[(size_t)(n0 + ty + r) * K + k0 + tx] = f2bf(tile[tx][ty + r]);
}

// Merged transpose for the 35 attention 256x256 weights (5 groups x 7 mods).
__global__ __launch_bounds__(256) void transpose_qkv(
    const float* __restrict__ Wq, const float* __restrict__ Wk,
    const float* __restrict__ Wv, const float* __restrict__ Gw,
    const float* __restrict__ Ow, ushort* __restrict__ out)
{
    __shared__ float tile[32][33];
    int z = blockIdx.z;
    const float* base = (z < 7) ? Wq : (z < 14) ? Wk : (z < 21) ? Wv
                       : (z < 28) ? Gw : Ow;
    const float* W = base + (size_t)(z % 7) * 65536;
    ushort* O = out + (size_t)z * 65536;
    int n0 = blockIdx.x * 32, k0 = blockIdx.y * 32;
    int tx = threadIdx.x & 31, ty = threadIdx.x >> 5;
#pragma unroll
    for (int r = 0; r < 32; r += 8)
        tile[ty + r][tx] = W[(size_t)(k0 + ty + r) * 256 + n0 + tx];
    __syncthreads();
#pragma unroll
    for (int r = 0; r < 32; r += 8)
        O[(size_t)(n0 + ty + r) * 256 + k0 + tx] = f2bf(tile[tx][ty + r]);
}

// ---------------------------------------------------------------------------
// Batched LayerNorm: 4 rows/block (one per wave). Module by LOCAL row chunk.
// ---------------------------------------------------------------------------
__global__ __launch_bounds__(256) void ln_bat(
    const float* __restrict__ x, ushort* __restrict__ dst,
    const float* __restrict__ g, const float* __restrict__ b,
    int rowOff, int4 mods)
{
    int wave = threadIdx.x >> 6, lane = threadIdx.x & 63;
    int lrow = blockIdx.x * 4 + wave;
    int gr   = rowOff + lrow;
    int mod  = comp(mods, lrow >> 11);

    float4 v = ((const float4*)(x + (size_t)gr * 256))[lane];
    float s  = v.x + v.y + v.z + v.w;
    float sq = v.x * v.x + v.y * v.y + v.z * v.z + v.w * v.w;
#pragma unroll
    for (int off = 1; off <= 32; off <<= 1) {
        s  += __shfl_xor(s, off);
        sq += __shfl_xor(sq, off);
    }
    float mean = s * (1.0f / 256.0f);
    float var  = sq * (1.0f / 256.0f) - mean * mean;
    float rstd = rsqrtf(var + 1e-5f);

    float4 g4 = ((const float4*)(g + mod * 256))[lane];
    float4 b4 = ((const float4*)(b + mod * 256))[lane];
    ushort4 o;
    o.x = f2bf((v.x - mean) * rstd * g4.x + b4.x);
    o.y = f2bf((v.y - mean) * rstd * g4.y + b4.y);
    o.z = f2bf((v.z - mean) * rstd * g4.z + b4.z);
    o.w = f2bf((v.w - mean) * rstd * g4.w + b4.w);
    *(ushort4*)(dst + (size_t)gr * 256 + lane * 4) = o;
}

// Streaming staging: NR rows x 64 cols, granule swizzle cg = (lane&7)^r8.
template<int NR>
static __device__ __forceinline__ void stage(
    const ushort* src, int stride, ushort* lds, int wave, int lane)
{
    int r8 = lane >> 3;
    int cg = (lane & 7) ^ r8;
    const int NCH = NR / 8;
#pragma unroll
    for (int ii = 0; ii < NCH / 4; ++ii) {
        int ci = wave + ii * 4;
        gld16(src + (size_t)(ci * 8 + r8) * stride + cg * 8, lds + ci * 512);
    }
}

// ---------------------------------------------------------------------------
// Streaming BK=64 GEMM core (THE proven shape: 12 KB LDS at FM=1/FN=2 ->
// 4-8 resident blocks/CU; latency hidden by block TLP, not by pipeline).
// ---------------------------------------------------------------------------
template<int FM, int FN>
static __device__ __forceinline__ void mfma_core(
    const ushort* __restrict__ A, const ushort* __restrict__ B,
    int Kloop, int sA, int sB, ushort* As, ushort* Bs, f32x4 acc[FM][FN])
{
    int tid = threadIdx.x, wave = tid >> 6, lane = tid & 63;
    int wr = wave >> 1, wc = wave & 1, lr = lane & 15, q = lane >> 4;
    for (int k0 = 0; k0 < Kloop; k0 += 64) {
        stage<32 * FM>(A + k0, sA, As, wave, lane);
        stage<32 * FN>(B + k0, sB, Bs, wave, lane);
        __syncthreads();
        short8 af[2][FM], bf_[2][FN];
#pragma unroll
        for (int s = 0; s < 2; ++s) {
#pragma unroll
            for (int fm = 0; fm < FM; ++fm) {
                int row = (wr * FM + fm) * 16 + lr;
                af[s][fm] = *(const short8*)(As + row * 64 + ((s * 4 + q) ^ (row & 7)) * 8);
            }
#pragma unroll
            for (int fn = 0; fn < FN; ++fn) {
                int row = (wc * FN + fn) * 16 + lr;
                bf_[s][fn] = *(const short8*)(Bs + row * 64 + ((s * 4 + q) ^ (row & 7)) * 8);
            }
        }
#pragma unroll
        for (int s = 0; s < 2; ++s)
#pragma unroll
            for (int fm = 0; fm < FM; ++fm)
#pragma unroll
                for (int fn = 0; fn < FN; ++fn)
                    acc[fm][fn] = __builtin_amdgcn_mfma_f32_16x16x32_bf16(
                        af[s][fm], bf_[s][fn], acc[fm][fn], 0, 0, 0);
        __syncthreads();
    }
}

// ---------------------------------------------------------------------------
// Split-K streaming GEMM (FF2), fp32 atomicAdd epilogue (residual in outf).
// ---------------------------------------------------------------------------
template<int FM, int FN>
__global__ __launch_bounds__(256) void gemm_split(
    const ushort* __restrict__ A, const ushort* __restrict__ Wt,
    const float* __restrict__ bias, float* __restrict__ outf,
    int N, int Ktot, int Kseg, int4 mods)
{
    __shared__ __align__(16) ushort As[32 * FM * 64];
    __shared__ __align__(16) ushort Bs[32 * FN * 64];
    f32x4 acc[FM][FN];
#pragma unroll
    for (int i = 0; i < FM; ++i)
#pragma unroll
        for (int j = 0; j < FN; ++j) acc[i][j] = (f32x4){0.f, 0.f, 0.f, 0.f};

    int bm = blockIdx.x * 32 * FM, bn = blockIdx.y * 32 * FN, bz = blockIdx.z;
    int mod = comp(mods, bm >> 11);
    mfma_core<FM, FN>(A + (size_t)bm * Ktot + bz * Kseg,
                      Wt + (size_t)mod * N * Ktot + (size_t)bn * Ktot + bz * Kseg,
                      Kseg, Ktot, Ktot, As, Bs, acc);

    int wave = threadIdx.x >> 6, lane = threadIdx.x & 63;
    int wr = wave >> 1, wc = wave & 1, lr = lane & 15, q = lane >> 4;
#pragma unroll
    for (int fm = 0; fm < FM; ++fm) {
#pragma unroll
        for (int rr = 0; rr < 4; ++rr) {
            int row = bm + (wr * FM + fm) * 16 + q * 4 + rr;
#pragma unroll
            for (int fn = 0; fn < FN; ++fn) {
                int col = bn + (wc * FN + fn) * 16 + lr;
                float v = acc[fm][fn][rr];
                if (bz == 0) v += bias[mod * N + col];
                atomicAdd(outf + (size_t)row * N + col, v);
            }
        }
    }
}

// ---------------------------------------------------------------------------
// Streaming QKVG projection, 32x64 tile, 12 KB LDS.
// grid (rows/32, 16): sect = y>>2, bn = (y&3)*64.
// Q/K/G -> big[row][1024] sections 0,1,3.  V -> vt[chunk][h][ch][row].
// ---------------------------------------------------------------------------
__global__ __launch_bounds__(256) void qkvg_st(
    const ushort* __restrict__ t, const ushort* __restrict__ wT,
    const float* __restrict__ gb, ushort* __restrict__ big,
    ushort* __restrict__ vt, int4 qoff, int4 kvoff, int4 wmods)
{
    __shared__ __align__(16) ushort As[32 * 64];   // 4 KB
    __shared__ __align__(16) ushort Bs[64 * 64];   // 8 KB

    int bm = blockIdx.x * 32;
    int sect = blockIdx.y >> 2, bn = (blockIdx.y & 3) * 64;
    int chunk = bm >> 11, lrow = bm & 2047;
    int wmod = comp(wmods, chunk);
    int asrc = ((sect == 0) ? comp(qoff, chunk) : comp(kvoff, chunk)) + lrow;

    f32x4 acc[1][2];
    acc[0][0] = (f32x4){0.f, 0.f, 0.f, 0.f};
    acc[0][1] = (f32x4){0.f, 0.f, 0.f, 0.f};
    mfma_core<1, 2>(t + (size_t)asrc * 256,
                    wT + (size_t)(sect * 7 + wmod) * 65536 + (size_t)bn * 256,
                    256, 256, 256, As, Bs, acc);

    int wave = threadIdx.x >> 6, lane = threadIdx.x & 63;
    int wr = wave >> 1, wc = wave & 1, lr = lane & 15, q = lane >> 4;
    if (sect == 2) {
#pragma unroll
        for (int fn = 0; fn < 2; ++fn) {
            int col = bn + (wc * 2 + fn) * 16 + lr;
            int hh = col >> 6, ch = col & 63;
            int row0 = lrow + wr * 16 + q * 4;
            ushort4 w;
            w.x = f2bf(acc[0][fn][0]); w.y = f2bf(acc[0][fn][1]);
            w.z = f2bf(acc[0][fn][2]); w.w = f2bf(acc[0][fn][3]);
            *(ushort4*)(vt + ((size_t)((chunk * 4 + hh) * 64 + ch)) * 2048 + row0) = w;
        }
    } else {
#pragma unroll
        for (int rr = 0; rr < 4; ++rr) {
            int rloc = wr * 16 + q * 4 + rr;
#pragma unroll
            for (int fn = 0; fn < 2; ++fn) {
                int col = bn + (wc * 2 + fn) * 16 + lr;
                float v = acc[0][fn][rr];
                if (sect == 3) v = 1.0f / (1.0f + __expf(-(v + gb[wmod * 256 + col])));
                big[(size_t)(chunk * 2048 + lrow + rloc) * 1024 + sect * 256 + col] = f2bf(v);
            }
        }
    }
}

// ---------------------------------------------------------------------------
// Streaming FF up-proj, 32x64 tile, 12 KB LDS. grid (rows/32, 32).
// ---------------------------------------------------------------------------
__global__ __launch_bounds__(256) void ff1_st(
    const ushort* __restrict__ t, const ushort* __restrict__ W1,
    const float* __restrict__ fb1, ushort* __restrict__ outb, int4 fmods)
{
    __shared__ __align__(16) ushort As[32 * 64];   // 4 KB
    __shared__ __align__(16) ushort Bs[64 * 64];   // 8 KB

    int bm = blockIdx.x * 32, bn = blockIdx.y * 64;
    int mod = comp(fmods, bm >> 11);

    f32x4 acc[1][2];
    acc[0][0] = (f32x4){0.f, 0.f, 0.f, 0.f};
    acc[0][1] = (f32x4){0.f, 0.f, 0.f, 0.f};
    mfma_core<1, 2>(t + (size_t)bm * 256,
                    W1 + (size_t)mod * 524288 + (size_t)bn * 256,
                    256, 256, 256, As, Bs, acc);

    int wave = threadIdx.x >> 6, lane = threadIdx.x & 63;
    int wr = wave >> 1, wc = wave & 1, lr = lane & 15, q = lane >> 4;
#pragma unroll
    for (int rr = 0; rr < 4; ++rr) {
        int row = bm + wr * 16 + q * 4 + rr;
#pragma unroll
        for (int fn = 0; fn < 2; ++fn) {
            int col = bn + (wc * 2 + fn) * 16 + lr;
            float v = acc[0][fn][rr] + fb1[mod * 2048 + col];
            outb[(size_t)row * 2048 + col] = f2bf(fmaxf(v, 0.0f));
        }
    }
}

// ---------------------------------------------------------------------------
// Fused banded attention + out-projection (+ optional fused ff-LayerNorm).
// oproj reads Wo rows DIRECTLY from global (L2-resident): the staged-LDS
// form had zero inter-wave reuse (row = oc*64+h*16+lr unique per wave), and
// the stage->vmcnt(0)->barrier chain x4 was the in-kernel serial pathology.
// Address equivalence Ws-swizzled == Wo[wrow*256+(s*4+q)*8] HW-verified (R1).
// LDS 50 KB -> 17.7 KB: 3 -> ~4 blocks/CU; 7 barriers + 4 drains removed.
// ---------------------------------------------------------------------------
__global__ __launch_bounds__(256) void attn_op(
    const ushort* __restrict__ big, const ushort* __restrict__ vt,
    const ushort* __restrict__ woT, const float* __restrict__ aOb,
    float* __restrict__ X, int4 orow, int4 wmods,
    const float* __restrict__ ffg, const float* __restrict__ ffb,
    ushort* __restrict__ tdst, int4 fmods, int fuseLN)
{
    __shared__ __align__(16) ushort smem[8832];      // 17.7 KB
    ushort* P  = smem;                    // 4*16*72 (dead after PV -> reused as sred)
    float*  lw = (float*)(smem + 4608);   // 64 floats
    ushort* ab = smem + 4736;             // 16*256 swizzled

    int tile = blockIdx.x;
    int chunk = tile >> 7, lt = tile & 127;
    int r0 = lt * 16, s0 = r0 & 1023, seqb = r0 & 1024;
    int t0 = s0 - 16; t0 = t0 < 0 ? 0 : (t0 > SEQ - 48 ? SEQ - 48 : t0);
    int mod = comp(wmods, chunk);
    int h = threadIdx.x >> 6, lane = threadIdx.x & 63;
    int lr = lane & 15, q = lane >> 4;
    size_t rowbase = (size_t)(chunk * 2048 + r0);
    size_t kvbase  = (size_t)(chunk * 2048 + seqb + t0);

    // S = Q K^T
    short8 aq[2];
#pragma unroll
    for (int s = 0; s < 2; ++s)
        aq[s] = *(const short8*)(big + (rowbase + lr) * 1024 + h * 64 + s * 32 + q * 8);
    f32x4 sc[3];
#pragma unroll
    for (int kt = 0; kt < 3; ++kt) {
        sc[kt] = (f32x4){0.f, 0.f, 0.f, 0.f};
        const ushort* kr = big + (kvbase + kt * 16 + lr) * 1024 + 256 + h * 64;
#pragma unroll
        for (int s = 0; s < 2; ++s)
            sc[kt] = __builtin_amdgcn_mfma_f32_16x16x32_bf16(
                aq[s], *(const short8*)(kr + s * 32 + q * 8), sc[kt], 0, 0, 0);
    }
    // zero P pad cols 48..63
    { int zr = lane >> 2, zc = 48 + (lane & 3) * 4;
      *(ushort4*)(P + h * 1152 + zr * 72 + zc) = (ushort4){0, 0, 0, 0}; }
    // mask + softmax (rows=queries, cols=keys)
    float pv[3][4], lsum[4];
#pragma unroll
    for (int r = 0; r < 4; ++r) {
        int sq = s0 + q * 4 + r;
#pragma unroll
        for (int kt = 0; kt < 3; ++kt) {
            int tt = t0 + kt * 16 + lr;
            int d = tt - sq;
            pv[kt][r] = (d <= WIN && d >= -WIN) ? sc[kt][r] * 0.125f : -1e30f;
        }
        float m = fmaxf(pv[0][r], fmaxf(pv[1][r], pv[2][r]));
#pragma unroll
        for (int off = 1; off <= 8; off <<= 1) m = fmaxf(m, __shfl_xor(m, off));
        float l = 0.f;
#pragma unroll
        for (int kt = 0; kt < 3; ++kt) { float p = __expf(pv[kt][r] - m); pv[kt][r] = p; l += p; }
#pragma unroll
        for (int off = 1; off <= 8; off <<= 1) l += __shfl_xor(l, off);
        lsum[r] = l;
    }
#pragma unroll
    for (int r = 0; r < 4; ++r)
#pragma unroll
        for (int kt = 0; kt < 3; ++kt)
            P[h * 1152 + (q * 4 + r) * 72 + kt * 16 + lr] = f2bf(pv[kt][r]);
    if (lr == 0) {
#pragma unroll
        for (int r = 0; r < 4; ++r) lw[h * 16 + q * 4 + r] = lsum[r];
    }
    __syncthreads();

    // O = P @ V -> D[query][ch]; apply 1/l and G; store swizzled bf16 to ab
#pragma unroll
    for (int ct = 0; ct < 4; ++ct) {
        f32x4 o = (f32x4){0.f, 0.f, 0.f, 0.f};
#pragma unroll
        for (int s = 0; s < 2; ++s) {
            short8 av = *(const short8*)(vt +
                ((size_t)((chunk * 4 + h) * 64 + ct * 16 + lr)) * 2048 +
                seqb + t0 + s * 32 + q * 8);
            short8 bp = *(const short8*)(P + h * 1152 + lr * 72 + s * 32 + q * 8);
            o = __builtin_amdgcn_mfma_f32_16x16x32_bf16(bp, av, o, 0, 0, 0);
        }
        int ch = h * 64 + ct * 16 + lr;
#pragma unroll
        for (int r = 0; r < 4; ++r) {
            int qr = q * 4 + r;
            float gv = bf2f(big[(rowbase + qr) * 1024 + 768 + ch]);
            float val = o[r] * (1.0f / lw[h * 16 + qr]) * gv;
            ab[qr * 256 + ((((ch >> 3) ^ (qr & 7)) << 3) | (ch & 7))] = f2bf(val);
        }
    }
    __syncthreads();   // ab complete (all waves); P is dead from here

    // oproj (barrier-free): acc[oc][r] = (ab @ Wo^T)[q*4+r][oc*64+h*16+lr]
    short8 af[8];
#pragma unroll
    for (int s = 0; s < 8; ++s)
        af[s] = *(const short8*)(ab + lr * 256 + (((s * 4 + q) ^ (lr & 7)) << 3));
    int xrow0 = comp(orow, chunk) + r0;
    const ushort* Wo = woT + (size_t)mod * 65536;
    float accs[4][4];
#pragma unroll
    for (int oc = 0; oc < 4; ++oc) {
        int col = oc * 64 + h * 16 + lr;
        const ushort* wrow = Wo + (size_t)col * 256;
        f32x4 acc = (f32x4){0.f, 0.f, 0.f, 0.f};
#pragma unroll
        for (int s = 0; s < 8; ++s) {
            short8 bf_ = *(const short8*)(wrow + (s * 4 + q) * 8);
            acc = __builtin_amdgcn_mfma_f32_16x16x32_bf16(af[s], bf_, acc, 0, 0, 0);
        }
#pragma unroll
        for (int r = 0; r < 4; ++r) accs[oc][r] = acc[r];
    }

    if (!fuseLN) {
#pragma unroll
        for (int oc = 0; oc < 4; ++oc) {
            int col = oc * 64 + h * 16 + lr;
            float bias = aOb[mod * 256 + col];
#pragma unroll
            for (int r = 0; r < 4; ++r)
                atomicAdd(X + (size_t)(xrow0 + q * 4 + r) * 256 + col, accs[oc][r] + bias);
        }
        return;
    }

    // -------- fused residual + ff-LayerNorm (sole-writer rows) --------
    float xv[4][4];            // [oc][r]
    float s1[4] = {0.f, 0.f, 0.f, 0.f}, s2[4] = {0.f, 0.f, 0.f, 0.f};
#pragma unroll
    for (int oc = 0; oc < 4; ++oc) {
        int col = oc * 64 + h * 16 + lr;
        float bias = aOb[mod * 256 + col];
#pragma unroll
        for (int r = 0; r < 4; ++r) {
            size_t idx = (size_t)(xrow0 + q * 4 + r) * 256 + col;
            float v = X[idx] + accs[oc][r] + bias;
            X[idx] = v;
            xv[oc][r] = v;
            s1[r] += v;
            s2[r] += v * v;
        }
    }
#pragma unroll
    for (int off = 1; off <= 8; off <<= 1) {
#pragma unroll
        for (int r = 0; r < 4; ++r) {
            s1[r] += __shfl_xor(s1[r], off);
            s2[r] += __shfl_xor(s2[r], off);
        }
    }
    // sred reuses P (dead since ab-complete barrier). Per-wave-disjoint
    // writes; the barrier below orders all writes before the reads.
    float* sred = (float*)P;   // [16 rows][4 waves][2]
    if (lr == 0) {
#pragma unroll
        for (int r = 0; r < 4; ++r) {
            sred[(q * 4 + r) * 8 + h * 2 + 0] = s1[r];
            sred[(q * 4 + r) * 8 + h * 2 + 1] = s2[r];
        }
    }
    __syncthreads();
    int fmod = comp(fmods, chunk);
#pragma unroll
    for (int r = 0; r < 4; ++r) {
        int rw = q * 4 + r;
        float t1 = sred[rw * 8 + 0] + sred[rw * 8 + 2] + sred[rw * 8 + 4] + sred[rw * 8 + 6];
        float t2 = sred[rw * 8 + 1] + sred[rw * 8 + 3] + sred[rw * 8 + 5] + sred[rw * 8 + 7];
        float mean = t1 * (1.0f / 256.0f);
        float var  = t2 * (1.0f / 256.0f) - mean * mean;
        float rstd = rsqrtf(var + 1e-5f);
#pragma unroll
        for (int oc = 0; oc < 4; ++oc) {
            int col = oc * 64 + h * 16 + lr;
            tdst[(size_t)(xrow0 + rw) * 256 + col] =
                f2bf((xv[oc][r] - mean) * rstd * ffg[fmod * 256 + col] + ffb[fmod * 256 + col]);
        }
    }
}

// ---------------------------------------------------------------------------
// Orchestration
// ---------------------------------------------------------------------------
extern "C" void kernel_launch(void* const* d_in, const int* in_sizes, int n_in,
                              void* d_out, int out_size, void* d_ws, size_t ws_size,
                              hipStream_t stream)
{
    const float* inL   = (const float*)d_in[0];
    const float* inN   = (const float*)d_in[1];
    const float* inO   = (const float*)d_in[2];
    const float* aWq   = (const float*)d_in[4];
    const float* aWk   = (const float*)d_in[5];
    const float* aWv   = (const float*)d_in[6];
    const float* aGw   = (const float*)d_in[7];
    const float* aGb   = (const float*)d_in[8];
    const float* aOw   = (const float*)d_in[9];
    const float* aOb   = (const float*)d_in[10];
    const float* ln_g  = (const float*)d_in[11];
    const float* ln_b  = (const float*)d_in[12];
    const float* ff_g  = (const float*)d_in[13];
    const float* ff_b  = (const float*)d_in[14];
    const float* ff_w1 = (const float*)d_in[15];
    const float* ff_b1 = (const float*)d_in[16];
    const float* ff_w2 = (const float*)d_in[17];
    const float* ff_b2 = (const float*)d_in[18];

    const size_t TD = (size_t)2048 * DIM;
    float* X = (float*)d_out;               // [6144][256]: L | N | O

    ushort* ws  = (ushort*)d_ws;
    ushort* wT  = ws;                       // 35 x 65536 (q0..6,k,v,g,o)
    ushort* woT = wT + 28 * 65536;          // o-proj weights (within wT)
    ushort* w1T = wT + 35 * 65536;          // 6x [2048][256]
    ushort* w2T = w1T + 6 * 524288;         // 6x [256][2048]
    ushort* t   = w2T + 6 * 524288;         // [6144][256] LN outputs
    ushort* big = t + 6144 * 256;           // QKVG [6144][1024] / FF hidden
    ushort* vt  = big + (size_t)6144 * 2048;// V^T: 3 chunks x 4h x 64ch x 2048

    transpose_qkv<<<dim3(8, 8, 35), 256, 0, stream>>>(aWq, aWk, aWv, aGw, aOw, wT);
    transpose_bf16<<<dim3(64, 8, 6), 256, 0, stream>>>(ff_w1, w1T, 256, 2048);
    transpose_bf16<<<dim3(8, 64, 6), 256, 0, stream>>>(ff_w2, w2T, 2048, 256);

    hipMemcpyAsync(X,          inL, TD * sizeof(float), hipMemcpyDeviceToDevice, stream);
    hipMemcpyAsync(X + TD,     inN, TD * sizeof(float), hipMemcpyDeviceToDevice, stream);
    hipMemcpyAsync(X + 2 * TD, inO, TD * sizeof(float), hipMemcpyDeviceToDevice, stream);

    auto ffblock = [&](int nrows, int rowOff, int4 fmods, bool needLN) {
        if (needLN)
            ln_bat<<<dim3(nrows / 4), 256, 0, stream>>>(X, t, ff_g, ff_b, rowOff, fmods);
        ff1_st<<<dim3(nrows / 32, 32), 256, 0, stream>>>(
            t + (size_t)rowOff * 256, w1T, ff_b1, big, fmods);
        gemm_split<1, 2><<<dim3(nrows / 32, 4, 4), 256, 0, stream>>>(
            big, w2T, ff_b2, X + (size_t)rowOff * 256, 256, 2048, 512, fmods);
    };

    for (int it = 0; it < 2; ++it) {
        // ---- Phase A: self-attention + FF on L,N,O (mods 0,1,2) ----
        ln_bat<<<dim3(1536), 256, 0, stream>>>(X, t, ln_g, ln_b, 0, make_int4(0, 1, 2, 0));
        qkvg_st<<<dim3(192, 16), 256, 0, stream>>>(
            t, wT, aGb, big, vt,
            make_int4(0, 2048, 4096, 0), make_int4(0, 2048, 4096, 0),
            make_int4(0, 1, 2, 0));
        attn_op<<<dim3(384), 256, 0, stream>>>(
            big, vt, woT, aOb, X, make_int4(0, 2048, 4096, 0), make_int4(0, 1, 2, 0),
            ff_g, ff_b, t, make_int4(0, 1, 2, 0), 1);
        ffblock(6144, 0, make_int4(0, 1, 2, 0), false);

        // ---- Phase B: L,N cross-attend tO (mods 3,4; ln by src chunk 4,5,3) ----
        ln_bat<<<dim3(1536), 256, 0, stream>>>(X, t, ln_g, ln_b, 0, make_int4(4, 5, 3, 0));
        qkvg_st<<<dim3(128, 16), 256, 0, stream>>>(
            t, wT, aGb, big, vt,
            make_int4(0, 2048, 0, 0), make_int4(4096, 4096, 0, 0),
            make_int4(3, 4, 0, 0));
        attn_op<<<dim3(256), 256, 0, stream>>>(
            big, vt, woT, aOb, X, make_int4(0, 2048, 0, 0), make_int4(3, 4, 0, 0),
            ff_g, ff_b, t, make_int4(3, 4, 0, 0), 1);
        ffblock(4096, 0, make_int4(3, 4, 0, 0), false);

        // ---- Phase C: O += att5(tO,tN) + att6(tO,tL); FF(5,O) ----
        ln_bat<<<dim3(1536), 256, 0, stream>>>(X, t, ln_g, ln_b, 0, make_int4(6, 7, 8, 0));
        qkvg_st<<<dim3(128, 16), 256, 0, stream>>>(
            t, wT, aGb, big, vt,
            make_int4(4096, 4096, 0, 0), make_int4(2048, 0, 0, 0),
            make_int4(5, 6, 0, 0));
        attn_op<<<dim3(256), 256, 0, stream>>>(
            big, vt, woT, aOb, X, make_int4(4096, 4096, 0, 0), make_int4(5, 6, 0, 0),
            ff_g, ff_b, t, make_int4(5, 0, 0, 0), 0);
        ffblock(2048, 4096, make_int4(5, 0, 0, 0), true);
    }
}

// Round 9
// 488.809 us; speedup vs baseline: 1.0933x; 1.0136x over previous
//
#include <hip/hip_runtime.h>
#include <math.h>

#define SEQ  1024
#define DIM  256
#define WIN  10

typedef __attribute__((ext_vector_type(8))) short  short8;
typedef __attribute__((ext_vector_type(4))) float  f32x4;

static __device__ __forceinline__ float bf2f(ushort u) {
    unsigned v = ((unsigned)u) << 16;
    return __builtin_bit_cast(float, v);
}
static __device__ __forceinline__ ushort f2bf(float f) {
    unsigned x = __builtin_bit_cast(unsigned, f);
    unsigned r = x + 0x7fffu + ((x >> 16) & 1u);
    return (ushort)(r >> 16);
}
static __device__ __forceinline__ int comp(int4 v, int i) {
    switch (i & 3) { case 0: return v.x; case 1: return v.y;
                     case 2: return v.z; default: return v.w; }
}
static __device__ __forceinline__ void gld16(const ushort* g, ushort* l) {
    __builtin_amdgcn_global_load_lds(
        (const __attribute__((address_space(1))) void*)g,
        (__attribute__((address_space(3))) void*)l, 16, 0, 0);
}

// ---------------------------------------------------------------------------
// fp32 [z][K][N] -> bf16 [z][N][K] transposes
// ---------------------------------------------------------------------------
__global__ __launch_bounds__(256) void transpose_bf16(
    const float* __restrict__ in, ushort* __restrict__ out, int K, int N)
{
    __shared__ float tile[32][33];
    const float* W = in + (size_t)blockIdx.z * K * N;
    ushort* O = out + (size_t)blockIdx.z * K * N;
    int n0 = blockIdx.x * 32, k0 = blockIdx.y * 32;
    int tx = threadIdx.x & 31, ty = threadIdx.x >> 5;
#pragma unroll
    for (int r = 0; r < 32; r += 8)
        tile[ty + r][tx] = W[(size_t)(k0 + ty + r) * N + n0 + tx];
    __syncthreads();
#pragma unroll
    for (int r = 0; r < 32; r += 8)
        O[(size_t)(n0 + ty + r) * K + k0 + tx] = f2bf(tile[tx][ty + r]);
}

// Merged transpose for the 35 attention 256x256 weights (5 groups x 7 mods).
__global__ __launch_bounds__(256) void transpose_qkv(
    const float* __restrict__ Wq, const float* __restrict__ Wk,
    const float* __restrict__ Wv, const float* __restrict__ Gw,
    const float* __restrict__ Ow, ushort* __restrict__ out)
{
    __shared__ float tile[32][33];
    int z = blockIdx.z;
    const float* base = (z < 7) ? Wq : (z < 14) ? Wk : (z < 21) ? Wv
                       : (z < 28) ? Gw : Ow;
    const float* W = base + (size_t)(z % 7) * 65536;
    ushort* O = out + (size_t)z * 65536;
    int n0 = blockIdx.x * 32, k0 = blockIdx.y * 32;
    int tx = threadIdx.x & 31, ty = threadIdx.x >> 5;
#pragma unroll
    for (int r = 0; r < 32; r += 8)
        tile[ty + r][tx] = W[(size_t)(k0 + ty + r) * 256 + n0 + tx];
    __syncthreads();
#pragma unroll
    for (int r = 0; r < 32; r += 8)
        O[(size_t)(n0 + ty + r) * 256 + k0 + tx] = f2bf(tile[tx][ty + r]);
}

// ---------------------------------------------------------------------------
// Batched LayerNorm: 4 rows/block (one per wave). Module by LOCAL row chunk.
// ---------------------------------------------------------------------------
__global__ __launch_bounds__(256) void ln_bat(
    const float* __restrict__ x, ushort* __restrict__ dst,
    const float* __restrict__ g, const float* __restrict__ b,
    int rowOff, int4 mods)
{
    int wave = threadIdx.x >> 6, lane = threadIdx.x & 63;
    int lrow = blockIdx.x * 4 + wave;
    int gr   = rowOff + lrow;
    int mod  = comp(mods, lrow >> 11);

    float4 v = ((const float4*)(x + (size_t)gr * 256))[lane];
    float s  = v.x + v.y + v.z + v.w;
    float sq = v.x * v.x + v.y * v.y + v.z * v.z + v.w * v.w;
#pragma unroll
    for (int off = 1; off <= 32; off <<= 1) {
        s  += __shfl_xor(s, off);
        sq += __shfl_xor(sq, off);
    }
    float mean = s * (1.0f / 256.0f);
    float var  = sq * (1.0f / 256.0f) - mean * mean;
    float rstd = rsqrtf(var + 1e-5f);

    float4 g4 = ((const float4*)(g + mod * 256))[lane];
    float4 b4 = ((const float4*)(b + mod * 256))[lane];
    ushort4 o;
    o.x = f2bf((v.x - mean) * rstd * g4.x + b4.x);
    o.y = f2bf((v.y - mean) * rstd * g4.y + b4.y);
    o.z = f2bf((v.z - mean) * rstd * g4.z + b4.z);
    o.w = f2bf((v.w - mean) * rstd * g4.w + b4.w);
    *(ushort4*)(dst + (size_t)gr * 256 + lane * 4) = o;
}

// ---------------------------------------------------------------------------
// Full-K (=256) staging: 64 rows x 256 cols bf16 -> 32 KB LDS, XOR-8 chunk
// swizzle p = c ^ (row&7). ONE barrier total (caller syncs). (attn_op Ws)
// ---------------------------------------------------------------------------
static __device__ __forceinline__ void stage_fk(
    const ushort* __restrict__ src, ushort* lds, int wave, int lane)
{
#pragma unroll
    for (int ii = 0; ii < 8; ++ii) {
        int i = wave + ii * 4;
        int o = i * 512 + lane * 8;
        int row = o >> 8;
        int p = (o >> 3) & 31;
        int c = p ^ (row & 7);
        gld16(src + (size_t)row * 256 + c * 8, lds + i * 512);
    }
}

// Streaming staging: NR rows x 64 cols, granule swizzle cg = (lane&7)^r8.
template<int NR>
static __device__ __forceinline__ void stage(
    const ushort* src, int stride, ushort* lds, int wave, int lane)
{
    int r8 = lane >> 3;
    int cg = (lane & 7) ^ r8;
    const int NCH = NR / 8;
#pragma unroll
    for (int ii = 0; ii < NCH / 4; ++ii) {
        int ci = wave + ii * 4;
        gld16(src + (size_t)(ci * 8 + r8) * stride + cg * 8, lds + ci * 512);
    }
}

// ---------------------------------------------------------------------------
// Streaming BK=64 GEMM core (THE proven shape: 12 KB LDS at FM=1/FN=2 ->
// 4-8 resident blocks/CU; latency hidden by block TLP, not by pipeline).
// ---------------------------------------------------------------------------
template<int FM, int FN>
static __device__ __forceinline__ void mfma_core(
    const ushort* __restrict__ A, const ushort* __restrict__ B,
    int Kloop, int sA, int sB, ushort* As, ushort* Bs, f32x4 acc[FM][FN])
{
    int tid = threadIdx.x, wave = tid >> 6, lane = tid & 63;
    int wr = wave >> 1, wc = wave & 1, lr = lane & 15, q = lane >> 4;
    for (int k0 = 0; k0 < Kloop; k0 += 64) {
        stage<32 * FM>(A + k0, sA, As, wave, lane);
        stage<32 * FN>(B + k0, sB, Bs, wave, lane);
        __syncthreads();
        short8 af[2][FM], bf_[2][FN];
#pragma unroll
        for (int s = 0; s < 2; ++s) {
#pragma unroll
            for (int fm = 0; fm < FM; ++fm) {
                int row = (wr * FM + fm) * 16 + lr;
                af[s][fm] = *(const short8*)(As + row * 64 + ((s * 4 + q) ^ (row & 7)) * 8);
            }
#pragma unroll
            for (int fn = 0; fn < FN; ++fn) {
                int row = (wc * FN + fn) * 16 + lr;
                bf_[s][fn] = *(const short8*)(Bs + row * 64 + ((s * 4 + q) ^ (row & 7)) * 8);
            }
        }
#pragma unroll
        for (int s = 0; s < 2; ++s)
#pragma unroll
            for (int fm = 0; fm < FM; ++fm)
#pragma unroll
                for (int fn = 0; fn < FN; ++fn)
                    acc[fm][fn] = __builtin_amdgcn_mfma_f32_16x16x32_bf16(
                        af[s][fm], bf_[s][fn], acc[fm][fn], 0, 0, 0);
        __syncthreads();
    }
}

// ---------------------------------------------------------------------------
// Split-K streaming GEMM (FF2), fp32 atomicAdd epilogue (residual in outf).
// ---------------------------------------------------------------------------
template<int FM, int FN>
__global__ __launch_bounds__(256) void gemm_split(
    const ushort* __restrict__ A, const ushort* __restrict__ Wt,
    const float* __restrict__ bias, float* __restrict__ outf,
    int N, int Ktot, int Kseg, int4 mods)
{
    __shared__ __align__(16) ushort As[32 * FM * 64];
    __shared__ __align__(16) ushort Bs[32 * FN * 64];
    f32x4 acc[FM][FN];
#pragma unroll
    for (int i = 0; i < FM; ++i)
#pragma unroll
        for (int j = 0; j < FN; ++j) acc[i][j] = (f32x4){0.f, 0.f, 0.f, 0.f};

    int bm = blockIdx.x * 32 * FM, bn = blockIdx.y * 32 * FN, bz = blockIdx.z;
    int mod = comp(mods, bm >> 11);
    mfma_core<FM, FN>(A + (size_t)bm * Ktot + bz * Kseg,
                      Wt + (size_t)mod * N * Ktot + (size_t)bn * Ktot + bz * Kseg,
                      Kseg, Ktot, Ktot, As, Bs, acc);

    int wave = threadIdx.x >> 6, lane = threadIdx.x & 63;
    int wr = wave >> 1, wc = wave & 1, lr = lane & 15, q = lane >> 4;
#pragma unroll
    for (int fm = 0; fm < FM; ++fm) {
#pragma unroll
        for (int rr = 0; rr < 4; ++rr) {
            int row = bm + (wr * FM + fm) * 16 + q * 4 + rr;
#pragma unroll
            for (int fn = 0; fn < FN; ++fn) {
                int col = bn + (wc * FN + fn) * 16 + lr;
                float v = acc[fm][fn][rr];
                if (bz == 0) v += bias[mod * N + col];
                atomicAdd(outf + (size_t)row * N + col, v);
            }
        }
    }
}

// ---------------------------------------------------------------------------
// Streaming QKVG projection, 32x64 tile, 12 KB LDS.
// grid (rows/32, 16): sect = y>>2, bn = (y&3)*64.
// Q/K/G -> big[row][1024] sections 0,1,3.  V -> vt[chunk][h][ch][row].
// ---------------------------------------------------------------------------
__global__ __launch_bounds__(256) void qkvg_st(
    const ushort* __restrict__ t, const ushort* __restrict__ wT,
    const float* __restrict__ gb, ushort* __restrict__ big,
    ushort* __restrict__ vt, int4 qoff, int4 kvoff, int4 wmods)
{
    __shared__ __align__(16) ushort As[32 * 64];   // 4 KB
    __shared__ __align__(16) ushort Bs[64 * 64];   // 8 KB

    int bm = blockIdx.x * 32;
    int sect = blockIdx.y >> 2, bn = (blockIdx.y & 3) * 64;
    int chunk = bm >> 11, lrow = bm & 2047;
    int wmod = comp(wmods, chunk);
    int asrc = ((sect == 0) ? comp(qoff, chunk) : comp(kvoff, chunk)) + lrow;

    f32x4 acc[1][2];
    acc[0][0] = (f32x4){0.f, 0.f, 0.f, 0.f};
    acc[0][1] = (f32x4){0.f, 0.f, 0.f, 0.f};
    mfma_core<1, 2>(t + (size_t)asrc * 256,
                    wT + (size_t)(sect * 7 + wmod) * 65536 + (size_t)bn * 256,
                    256, 256, 256, As, Bs, acc);

    int wave = threadIdx.x >> 6, lane = threadIdx.x & 63;
    int wr = wave >> 1, wc = wave & 1, lr = lane & 15, q = lane >> 4;
    if (sect == 2) {
#pragma unroll
        for (int fn = 0; fn < 2; ++fn) {
            int col = bn + (wc * 2 + fn) * 16 + lr;
            int hh = col >> 6, ch = col & 63;
            int row0 = lrow + wr * 16 + q * 4;
            ushort4 w;
            w.x = f2bf(acc[0][fn][0]); w.y = f2bf(acc[0][fn][1]);
            w.z = f2bf(acc[0][fn][2]); w.w = f2bf(acc[0][fn][3]);
            *(ushort4*)(vt + ((size_t)((chunk * 4 + hh) * 64 + ch)) * 2048 + row0) = w;
        }
    } else {
#pragma unroll
        for (int rr = 0; rr < 4; ++rr) {
            int rloc = wr * 16 + q * 4 + rr;
#pragma unroll
            for (int fn = 0; fn < 2; ++fn) {
                int col = bn + (wc * 2 + fn) * 16 + lr;
                float v = acc[0][fn][rr];
                if (sect == 3) v = 1.0f / (1.0f + __expf(-(v + gb[wmod * 256 + col])));
                big[(size_t)(chunk * 2048 + lrow + rloc) * 1024 + sect * 256 + col] = f2bf(v);
            }
        }
    }
}

// ---------------------------------------------------------------------------
// Streaming FF up-proj, 32x64 tile, 12 KB LDS. grid (rows/32, 32).
// ---------------------------------------------------------------------------
__global__ __launch_bounds__(256) void ff1_st(
    const ushort* __restrict__ t, const ushort* __restrict__ W1,
    const float* __restrict__ fb1, ushort* __restrict__ outb, int4 fmods)
{
    __shared__ __align__(16) ushort As[32 * 64];   // 4 KB
    __shared__ __align__(16) ushort Bs[64 * 64];   // 8 KB

    int bm = blockIdx.x * 32, bn = blockIdx.y * 64;
    int mod = comp(fmods, bm >> 11);

    f32x4 acc[1][2];
    acc[0][0] = (f32x4){0.f, 0.f, 0.f, 0.f};
    acc[0][1] = (f32x4){0.f, 0.f, 0.f, 0.f};
    mfma_core<1, 2>(t + (size_t)bm * 256,
                    W1 + (size_t)mod * 524288 + (size_t)bn * 256,
                    256, 256, 256, As, Bs, acc);

    int wave = threadIdx.x >> 6, lane = threadIdx.x & 63;
    int wr = wave >> 1, wc = wave & 1, lr = lane & 15, q = lane >> 4;
#pragma unroll
    for (int rr = 0; rr < 4; ++rr) {
        int row = bm + wr * 16 + q * 4 + rr;
#pragma unroll
        for (int fn = 0; fn < 2; ++fn) {
            int col = bn + (wc * 2 + fn) * 16 + lr;
            float v = acc[0][fn][rr] + fb1[mod * 2048 + col];
            outb[(size_t)row * 2048 + col] = f2bf(fmaxf(v, 0.0f));
        }
    }
}

// ---------------------------------------------------------------------------
// Fused banded attention + out-projection (+ optional fused ff-LayerNorm).
// Staged-Ws oproj (measured faster than direct-global Wo: R6 490.4 vs R8
// 495.5 -- global reads put VMEM latency on the MFMA dependency chain).
// ---------------------------------------------------------------------------
__global__ __launch_bounds__(256) void attn_op(
    const ushort* __restrict__ big, const ushort* __restrict__ vt,
    const ushort* __restrict__ woT, const float* __restrict__ aOb,
    float* __restrict__ X, int4 orow, int4 wmods,
    const float* __restrict__ ffg, const float* __restrict__ ffb,
    ushort* __restrict__ tdst, int4 fmods, int fuseLN)
{
    __shared__ __align__(16) ushort smem[25216];     // ~50 KB -> 3 blocks/CU
    ushort* P  = smem;                    // 4*16*72 (dead after PV -> reused as sred)
    float*  lw = (float*)(smem + 4608);   // 64 floats
    ushort* ab = smem + 4736;             // 16*256 swizzled
    ushort* Ws = smem + 8832;             // 64*256

    int tile = blockIdx.x;
    int chunk = tile >> 7, lt = tile & 127;
    int r0 = lt * 16, s0 = r0 & 1023, seqb = r0 & 1024;
    int t0 = s0 - 16; t0 = t0 < 0 ? 0 : (t0 > SEQ - 48 ? SEQ - 48 : t0);
    int mod = comp(wmods, chunk);
    int h = threadIdx.x >> 6, lane = threadIdx.x & 63;
    int lr = lane & 15, q = lane >> 4;
    size_t rowbase = (size_t)(chunk * 2048 + r0);
    size_t kvbase  = (size_t)(chunk * 2048 + seqb + t0);

    // S = Q K^T
    short8 aq[2];
#pragma unroll
    for (int s = 0; s < 2; ++s)
        aq[s] = *(const short8*)(big + (rowbase + lr) * 1024 + h * 64 + s * 32 + q * 8);
    f32x4 sc[3];
#pragma unroll
    for (int kt = 0; kt < 3; ++kt) {
        sc[kt] = (f32x4){0.f, 0.f, 0.f, 0.f};
        const ushort* kr = big + (kvbase + kt * 16 + lr) * 1024 + 256 + h * 64;
#pragma unroll
        for (int s = 0; s < 2; ++s)
            sc[kt] = __builtin_amdgcn_mfma_f32_16x16x32_bf16(
                aq[s], *(const short8*)(kr + s * 32 + q * 8), sc[kt], 0, 0, 0);
    }
    // zero P pad cols 48..63
    { int zr = lane >> 2, zc = 48 + (lane & 3) * 4;
      *(ushort4*)(P + h * 1152 + zr * 72 + zc) = (ushort4){0, 0, 0, 0}; }
    // mask + softmax (rows=queries, cols=keys)
    float pv[3][4], lsum[4];
#pragma unroll
    for (int r = 0; r < 4; ++r) {
        int sq = s0 + q * 4 + r;
#pragma unroll
        for (int kt = 0; kt < 3; ++kt) {
            int tt = t0 + kt * 16 + lr;
            int d = tt - sq;
            pv[kt][r] = (d <= WIN && d >= -WIN) ? sc[kt][r] * 0.125f : -1e30f;
        }
        float m = fmaxf(pv[0][r], fmaxf(pv[1][r], pv[2][r]));
#pragma unroll
        for (int off = 1; off <= 8; off <<= 1) m = fmaxf(m, __shfl_xor(m, off));
        float l = 0.f;
#pragma unroll
        for (int kt = 0; kt < 3; ++kt) { float p = __expf(pv[kt][r] - m); pv[kt][r] = p; l += p; }
#pragma unroll
        for (int off = 1; off <= 8; off <<= 1) l += __shfl_xor(l, off);
        lsum[r] = l;
    }
#pragma unroll
    for (int r = 0; r < 4; ++r)
#pragma unroll
        for (int kt = 0; kt < 3; ++kt)
            P[h * 1152 + (q * 4 + r) * 72 + kt * 16 + lr] = f2bf(pv[kt][r]);
    if (lr == 0) {
#pragma unroll
        for (int r = 0; r < 4; ++r) lw[h * 16 + q * 4 + r] = lsum[r];
    }
    __syncthreads();

    // O = P @ V -> D[query][ch]; apply 1/l and G; store swizzled bf16 to ab
#pragma unroll
    for (int ct = 0; ct < 4; ++ct) {
        f32x4 o = (f32x4){0.f, 0.f, 0.f, 0.f};
#pragma unroll
        for (int s = 0; s < 2; ++s) {
            short8 av = *(const short8*)(vt +
                ((size_t)((chunk * 4 + h) * 64 + ct * 16 + lr)) * 2048 +
                seqb + t0 + s * 32 + q * 8);
            short8 bp = *(const short8*)(P + h * 1152 + lr * 72 + s * 32 + q * 8);
            o = __builtin_amdgcn_mfma_f32_16x16x32_bf16(bp, av, o, 0, 0, 0);
        }
        int ch = h * 64 + ct * 16 + lr;
#pragma unroll
        for (int r = 0; r < 4; ++r) {
            int qr = q * 4 + r;
            float gv = bf2f(big[(rowbase + qr) * 1024 + 768 + ch]);
            float val = o[r] * (1.0f / lw[h * 16 + qr]) * gv;
            ab[qr * 256 + ((((ch >> 3) ^ (qr & 7)) << 3) | (ch & 7))] = f2bf(val);
        }
    }
    __syncthreads();   // ab complete (all waves); P is dead from here

    // oproj: acc[oc][r] = (ab @ Wo^T)[q*4+r][oc*64+h*16+lr]
    short8 af[8];
#pragma unroll
    for (int s = 0; s < 8; ++s)
        af[s] = *(const short8*)(ab + lr * 256 + (((s * 4 + q) ^ (lr & 7)) << 3));
    int xrow0 = comp(orow, chunk) + r0;
    const ushort* Wo = woT + (size_t)mod * 65536;
    float accs[4][4];
#pragma unroll
    for (int oc = 0; oc < 4; ++oc) {
        stage_fk(Wo + (size_t)(oc * 64) * 256, Ws, h, lane);
        __syncthreads();
        f32x4 acc = (f32x4){0.f, 0.f, 0.f, 0.f};
        int wrow = h * 16 + lr;
#pragma unroll
        for (int s = 0; s < 8; ++s) {
            short8 bf_ = *(const short8*)(Ws + wrow * 256 + (((s * 4 + q) ^ (wrow & 7)) << 3));
            acc = __builtin_amdgcn_mfma_f32_16x16x32_bf16(af[s], bf_, acc, 0, 0, 0);
        }
#pragma unroll
        for (int r = 0; r < 4; ++r) accs[oc][r] = acc[r];
        if (oc < 3) __syncthreads();   // last barrier redundant: Ws not reused
    }

    if (!fuseLN) {
#pragma unroll
        for (int oc = 0; oc < 4; ++oc) {
            int col = oc * 64 + h * 16 + lr;
            float bias = aOb[mod * 256 + col];
#pragma unroll
            for (int r = 0; r < 4; ++r)
                atomicAdd(X + (size_t)(xrow0 + q * 4 + r) * 256 + col, accs[oc][r] + bias);
        }
        return;
    }

    // -------- fused residual + ff-LayerNorm (sole-writer rows) --------
    float xv[4][4];            // [oc][r]
    float s1[4] = {0.f, 0.f, 0.f, 0.f}, s2[4] = {0.f, 0.f, 0.f, 0.f};
#pragma unroll
    for (int oc = 0; oc < 4; ++oc) {
        int col = oc * 64 + h * 16 + lr;
        float bias = aOb[mod * 256 + col];
#pragma unroll
        for (int r = 0; r < 4; ++r) {
            size_t idx = (size_t)(xrow0 + q * 4 + r) * 256 + col;
            float v = X[idx] + accs[oc][r] + bias;
            X[idx] = v;
            xv[oc][r] = v;
            s1[r] += v;
            s2[r] += v * v;
        }
    }
#pragma unroll
    for (int off = 1; off <= 8; off <<= 1) {
#pragma unroll
        for (int r = 0; r < 4; ++r) {
            s1[r] += __shfl_xor(s1[r], off);
            s2[r] += __shfl_xor(s2[r], off);
        }
    }
    float* sred = (float*)P;   // [16 rows][4 waves][2]
    __syncthreads();           // all waves past Ws reads before P reuse
    if (lr == 0) {
#pragma unroll
        for (int r = 0; r < 4; ++r) {
            sred[(q * 4 + r) * 8 + h * 2 + 0] = s1[r];
            sred[(q * 4 + r) * 8 + h * 2 + 1] = s2[r];
        }
    }
    __syncthreads();
    int fmod = comp(fmods, chunk);
#pragma unroll
    for (int r = 0; r < 4; ++r) {
        int rw = q * 4 + r;
        float t1 = sred[rw * 8 + 0] + sred[rw * 8 + 2] + sred[rw * 8 + 4] + sred[rw * 8 + 6];
        float t2 = sred[rw * 8 + 1] + sred[rw * 8 + 3] + sred[rw * 8 + 5] + sred[rw * 8 + 7];
        float mean = t1 * (1.0f / 256.0f);
        float var  = t2 * (1.0f / 256.0f) - mean * mean;
        float rstd = rsqrtf(var + 1e-5f);
#pragma unroll
        for (int oc = 0; oc < 4; ++oc) {
            int col = oc * 64 + h * 16 + lr;
            tdst[(size_t)(xrow0 + rw) * 256 + col] =
                f2bf((xv[oc][r] - mean) * rstd * ffg[fmod * 256 + col] + ffb[fmod * 256 + col]);
        }
    }
}

// ---------------------------------------------------------------------------
// Orchestration
// ---------------------------------------------------------------------------
extern "C" void kernel_launch(void* const* d_in, const int* in_sizes, int n_in,
                              void* d_out, int out_size, void* d_ws, size_t ws_size,
                              hipStream_t stream)
{
    const float* inL   = (const float*)d_in[0];
    const float* inN   = (const float*)d_in[1];
    const float* inO   = (const float*)d_in[2];
    const float* aWq   = (const float*)d_in[4];
    const float* aWk   = (const float*)d_in[5];
    const float* aWv   = (const float*)d_in[6];
    const float* aGw   = (const float*)d_in[7];
    const float* aGb   = (const float*)d_in[8];
    const float* aOw   = (const float*)d_in[9];
    const float* aOb   = (const float*)d_in[10];
    const float* ln_g  = (const float*)d_in[11];
    const float* ln_b  = (const float*)d_in[12];
    const float* ff_g  = (const float*)d_in[13];
    const float* ff_b  = (const float*)d_in[14];
    const float* ff_w1 = (const float*)d_in[15];
    const float* ff_b1 = (const float*)d_in[16];
    const float* ff_w2 = (const float*)d_in[17];
    const float* ff_b2 = (const float*)d_in[18];

    const size_t TD = (size_t)2048 * DIM;
    float* X = (float*)d_out;               // [6144][256]: L | N | O

    ushort* ws  = (ushort*)d_ws;
    ushort* wT  = ws;                       // 35 x 65536 (q0..6,k,v,g,o)
    ushort* woT = wT + 28 * 65536;          // o-proj weights (within wT)
    ushort* w1T = wT + 35 * 65536;          // 6x [2048][256]
    ushort* w2T = w1T + 6 * 524288;         // 6x [256][2048]
    ushort* t   = w2T + 6 * 524288;         // [6144][256] LN outputs
    ushort* big = t + 6144 * 256;           // QKVG [6144][1024] / FF hidden
    ushort* vt  = big + (size_t)6144 * 2048;// V^T: 3 chunks x 4h x 64ch x 2048

    transpose_qkv<<<dim3(8, 8, 35), 256, 0, stream>>>(aWq, aWk, aWv, aGw, aOw, wT);
    transpose_bf16<<<dim3(64, 8, 6), 256, 0, stream>>>(ff_w1, w1T, 256, 2048);
    transpose_bf16<<<dim3(8, 64, 6), 256, 0, stream>>>(ff_w2, w2T, 2048, 256);

    hipMemcpyAsync(X,          inL, TD * sizeof(float), hipMemcpyDeviceToDevice, stream);
    hipMemcpyAsync(X + TD,     inN, TD * sizeof(float), hipMemcpyDeviceToDevice, stream);
    hipMemcpyAsync(X + 2 * TD, inO, TD * sizeof(float), hipMemcpyDeviceToDevice, stream);

    auto ffblock = [&](int nrows, int rowOff, int4 fmods, bool needLN) {
        if (needLN)
            ln_bat<<<dim3(nrows / 4), 256, 0, stream>>>(X, t, ff_g, ff_b, rowOff, fmods);
        ff1_st<<<dim3(nrows / 32, 32), 256, 0, stream>>>(
            t + (size_t)rowOff * 256, w1T, ff_b1, big, fmods);
        gemm_split<1, 2><<<dim3(nrows / 32, 4, 4), 256, 0, stream>>>(
            big, w2T, ff_b2, X + (size_t)rowOff * 256, 256, 2048, 512, fmods);
    };

    for (int it = 0; it < 2; ++it) {
        // ---- Phase A: self-attention + FF on L,N,O (mods 0,1,2) ----
        ln_bat<<<dim3(1536), 256, 0, stream>>>(X, t, ln_g, ln_b, 0, make_int4(0, 1, 2, 0));
        qkvg_st<<<dim3(192, 16), 256, 0, stream>>>(
            t, wT, aGb, big, vt,
            make_int4(0, 2048, 4096, 0), make_int4(0, 2048, 4096, 0),
            make_int4(0, 1, 2, 0));
        attn_op<<<dim3(384), 256, 0, stream>>>(
            big, vt, woT, aOb, X, make_int4(0, 2048, 4096, 0), make_int4(0, 1, 2, 0),
            ff_g, ff_b, t, make_int4(0, 1, 2, 0), 1);
        ffblock(6144, 0, make_int4(0, 1, 2, 0), false);

        // ---- Phase B: L,N cross-attend tO (mods 3,4; ln by src chunk 4,5,3) ----
        ln_bat<<<dim3(1536), 256, 0, stream>>>(X, t, ln_g, ln_b, 0, make_int4(4, 5, 3, 0));
        qkvg_st<<<dim3(128, 16), 256, 0, stream>>>(
            t, wT, aGb, big, vt,
            make_int4(0, 2048, 0, 0), make_int4(4096, 4096, 0, 0),
            make_int4(3, 4, 0, 0));
        attn_op<<<dim3(256), 256, 0, stream>>>(
            big, vt, woT, aOb, X, make_int4(0, 2048, 0, 0), make_int4(3, 4, 0, 0),
            ff_g, ff_b, t, make_int4(3, 4, 0, 0), 1);
        ffblock(4096, 0, make_int4(3, 4, 0, 0), false);

        // ---- Phase C: O += att5(tO,tN) + att6(tO,tL); FF(5,O) ----
        ln_bat<<<dim3(1536), 256, 0, stream>>>(X, t, ln_g, ln_b, 0, make_int4(6, 7, 8, 0));
        qkvg_st<<<dim3(128, 16), 256, 0, stream>>>(
            t, wT, aGb, big, vt,
            make_int4(4096, 4096, 0, 0), make_int4(2048, 0, 0, 0),
            make_int4(5, 6, 0, 0));
        attn_op<<<dim3(256), 256, 0, stream>>>(
            big, vt, woT, aOb, X, make_int4(4096, 4096, 0, 0), make_int4(5, 6, 0, 0),
            ff_g, ff_b, t, make_int4(5, 0, 0, 0), 0);
        ffblock(2048, 4096, make_int4(5, 0, 0, 0), true);
    }
}

// Round 10
// 487.951 us; speedup vs baseline: 1.0952x; 1.0018x over previous
//
#include <hip/hip_runtime.h>
#include <math.h>

#define SEQ  1024
#define DIM  256
#define WIN  10

typedef __attribute__((ext_vector_type(8))) short  short8;
typedef __attribute__((ext_vector_type(4))) float  f32x4;

static __device__ __forceinline__ float bf2f(ushort u) {
    unsigned v = ((unsigned)u) << 16;
    return __builtin_bit_cast(float, v);
}
static __device__ __forceinline__ ushort f2bf(float f) {
    unsigned x = __builtin_bit_cast(unsigned, f);
    unsigned r = x + 0x7fffu + ((x >> 16) & 1u);
    return (ushort)(r >> 16);
}
static __device__ __forceinline__ int comp(int4 v, int i) {
    switch (i & 3) { case 0: return v.x; case 1: return v.y;
                     case 2: return v.z; default: return v.w; }
}
static __device__ __forceinline__ void gld16(const ushort* g, ushort* l) {
    __builtin_amdgcn_global_load_lds(
        (const __attribute__((address_space(1))) void*)g,
        (__attribute__((address_space(3))) void*)l, 16, 0, 0);
}

// ---------------------------------------------------------------------------
// fp32 [z][K][N] -> bf16 [z][N][K] transposes
// ---------------------------------------------------------------------------
__global__ __launch_bounds__(256) void transpose_bf16(
    const float* __restrict__ in, ushort* __restrict__ out, int K, int N)
{
    __shared__ float tile[32][33];
    const float* W = in + (size_t)blockIdx.z * K * N;
    ushort* O = out + (size_t)blockIdx.z * K * N;
    int n0 = blockIdx.x * 32, k0 = blockIdx.y * 32;
    int tx = threadIdx.x & 31, ty = threadIdx.x >> 5;
#pragma unroll
    for (int r = 0; r < 32; r += 8)
        tile[ty + r][tx] = W[(size_t)(k0 + ty + r) * N + n0 + tx];
    __syncthreads();
#pragma unroll
    for (int r = 0; r < 32; r += 8)
        O[(size_t)(n0 + ty + r) * K + k0 + tx] = f2bf(tile[tx][ty + r]);
}

// Merged transpose for the 35 attention 256x256 weights (5 groups x 7 mods).
__global__ __launch_bounds__(256) void transpose_qkv(
    const float* __restrict__ Wq, const float* __restrict__ Wk,
    const float* __restrict__ Wv, const float* __restrict__ Gw,
    const float* __restrict__ Ow, ushort* __restrict__ out)
{
    __shared__ float tile[32][33];
    int z = blockIdx.z;
    const float* base = (z < 7) ? Wq : (z < 14) ? Wk : (z < 21) ? Wv
                       : (z < 28) ? Gw : Ow;
    const float* W = base + (size_t)(z % 7) * 65536;
    ushort* O = out + (size_t)z * 65536;
    int n0 = blockIdx.x * 32, k0 = blockIdx.y * 32;
    int tx = threadIdx.x & 31, ty = threadIdx.x >> 5;
#pragma unroll
    for (int r = 0; r < 32; r += 8)
        tile[ty + r][tx] = W[(size_t)(k0 + ty + r) * 256 + n0 + tx];
    __syncthreads();
#pragma unroll
    for (int r = 0; r < 32; r += 8)
        O[(size_t)(n0 + ty + r) * 256 + k0 + tx] = f2bf(tile[tx][ty + r]);
}

// ---------------------------------------------------------------------------
// Batched LayerNorm: 4 rows/block (one per wave). Module by LOCAL row chunk.
// ---------------------------------------------------------------------------
__global__ __launch_bounds__(256) void ln_bat(
    const float* __restrict__ x, ushort* __restrict__ dst,
    const float* __restrict__ g, const float* __restrict__ b,
    int rowOff, int4 mods)
{
    int wave = threadIdx.x >> 6, lane = threadIdx.x & 63;
    int lrow = blockIdx.x * 4 + wave;
    int gr   = rowOff + lrow;
    int mod  = comp(mods, lrow >> 11);

    float4 v = ((const float4*)(x + (size_t)gr * 256))[lane];
    float s  = v.x + v.y + v.z + v.w;
    float sq = v.x * v.x + v.y * v.y + v.z * v.z + v.w * v.w;
#pragma unroll
    for (int off = 1; off <= 32; off <<= 1) {
        s  += __shfl_xor(s, off);
        sq += __shfl_xor(sq, off);
    }
    float mean = s * (1.0f / 256.0f);
    float var  = sq * (1.0f / 256.0f) - mean * mean;
    float rstd = rsqrtf(var + 1e-5f);

    float4 g4 = ((const float4*)(g + mod * 256))[lane];
    float4 b4 = ((const float4*)(b + mod * 256))[lane];
    ushort4 o;
    o.x = f2bf((v.x - mean) * rstd * g4.x + b4.x);
    o.y = f2bf((v.y - mean) * rstd * g4.y + b4.y);
    o.z = f2bf((v.z - mean) * rstd * g4.z + b4.z);
    o.w = f2bf((v.w - mean) * rstd * g4.w + b4.w);
    *(ushort4*)(dst + (size_t)gr * 256 + lane * 4) = o;
}

// ---------------------------------------------------------------------------
// Full-K (=256) staging: 64 rows x 256 cols bf16 -> 32 KB LDS, XOR-8 chunk
// swizzle p = c ^ (row&7). ONE barrier total (caller syncs). (attn_op Ws)
// ---------------------------------------------------------------------------
static __device__ __forceinline__ void stage_fk(
    const ushort* __restrict__ src, ushort* lds, int wave, int lane)
{
#pragma unroll
    for (int ii = 0; ii < 8; ++ii) {
        int i = wave + ii * 4;
        int o = i * 512 + lane * 8;
        int row = o >> 8;
        int p = (o >> 3) & 31;
        int c = p ^ (row & 7);
        gld16(src + (size_t)row * 256 + c * 8, lds + i * 512);
    }
}

// Streaming staging: NR rows x 64 cols, granule swizzle cg = (lane&7)^r8.
template<int NR>
static __device__ __forceinline__ void stage(
    const ushort* src, int stride, ushort* lds, int wave, int lane)
{
    int r8 = lane >> 3;
    int cg = (lane & 7) ^ r8;
    const int NCH = NR / 8;
#pragma unroll
    for (int ii = 0; ii < NCH / 4; ++ii) {
        int ci = wave + ii * 4;
        gld16(src + (size_t)(ci * 8 + r8) * stride + cg * 8, lds + ci * 512);
    }
}

// ---------------------------------------------------------------------------
// Streaming BK=64 GEMM core (THE proven shape: 12 KB LDS at FM=1/FN=2 ->
// 4-8 resident blocks/CU; latency hidden by block TLP, not by pipeline).
// ---------------------------------------------------------------------------
template<int FM, int FN>
static __device__ __forceinline__ void mfma_core(
    const ushort* __restrict__ A, const ushort* __restrict__ B,
    int Kloop, int sA, int sB, ushort* As, ushort* Bs, f32x4 acc[FM][FN])
{
    int tid = threadIdx.x, wave = tid >> 6, lane = tid & 63;
    int wr = wave >> 1, wc = wave & 1, lr = lane & 15, q = lane >> 4;
    for (int k0 = 0; k0 < Kloop; k0 += 64) {
        stage<32 * FM>(A + k0, sA, As, wave, lane);
        stage<32 * FN>(B + k0, sB, Bs, wave, lane);
        __syncthreads();
        short8 af[2][FM], bf_[2][FN];
#pragma unroll
        for (int s = 0; s < 2; ++s) {
#pragma unroll
            for (int fm = 0; fm < FM; ++fm) {
                int row = (wr * FM + fm) * 16 + lr;
                af[s][fm] = *(const short8*)(As + row * 64 + ((s * 4 + q) ^ (row & 7)) * 8);
            }
#pragma unroll
            for (int fn = 0; fn < FN; ++fn) {
                int row = (wc * FN + fn) * 16 + lr;
                bf_[s][fn] = *(const short8*)(Bs + row * 64 + ((s * 4 + q) ^ (row & 7)) * 8);
            }
        }
#pragma unroll
        for (int s = 0; s < 2; ++s)
#pragma unroll
            for (int fm = 0; fm < FM; ++fm)
#pragma unroll
                for (int fn = 0; fn < FN; ++fn)
                    acc[fm][fn] = __builtin_amdgcn_mfma_f32_16x16x32_bf16(
                        af[s][fm], bf_[s][fn], acc[fm][fn], 0, 0, 0);
        __syncthreads();
    }
}

// ---------------------------------------------------------------------------
// Split-K streaming GEMM (FF2), fp32 atomicAdd epilogue (residual in outf).
// ---------------------------------------------------------------------------
template<int FM, int FN>
__global__ __launch_bounds__(256) void gemm_split(
    const ushort* __restrict__ A, const ushort* __restrict__ Wt,
    const float* __restrict__ bias, float* __restrict__ outf,
    int N, int Ktot, int Kseg, int4 mods)
{
    __shared__ __align__(16) ushort As[32 * FM * 64];
    __shared__ __align__(16) ushort Bs[32 * FN * 64];
    f32x4 acc[FM][FN];
#pragma unroll
    for (int i = 0; i < FM; ++i)
#pragma unroll
        for (int j = 0; j < FN; ++j) acc[i][j] = (f32x4){0.f, 0.f, 0.f, 0.f};

    int bm = blockIdx.x * 32 * FM, bn = blockIdx.y * 32 * FN, bz = blockIdx.z;
    int mod = comp(mods, bm >> 11);
    mfma_core<FM, FN>(A + (size_t)bm * Ktot + bz * Kseg,
                      Wt + (size_t)mod * N * Ktot + (size_t)bn * Ktot + bz * Kseg,
                      Kseg, Ktot, Ktot, As, Bs, acc);

    int wave = threadIdx.x >> 6, lane = threadIdx.x & 63;
    int wr = wave >> 1, wc = wave & 1, lr = lane & 15, q = lane >> 4;
#pragma unroll
    for (int fm = 0; fm < FM; ++fm) {
#pragma unroll
        for (int rr = 0; rr < 4; ++rr) {
            int row = bm + (wr * FM + fm) * 16 + q * 4 + rr;
#pragma unroll
            for (int fn = 0; fn < FN; ++fn) {
                int col = bn + (wc * FN + fn) * 16 + lr;
                float v = acc[fm][fn][rr];
                if (bz == 0) v += bias[mod * N + col];
                atomicAdd(outf + (size_t)row * N + col, v);
            }
        }
    }
}

// ---------------------------------------------------------------------------
// Streaming QKVG projection, 32x64 tile, 12 KB LDS.
// grid (rows/32, 16): sect = y>>2, bn = (y&3)*64.
// Q/K/G -> big[row][1024] sections 0,1,3.  V -> vt[chunk][h][ch][row].
// ---------------------------------------------------------------------------
__global__ __launch_bounds__(256) void qkvg_st(
    const ushort* __restrict__ t, const ushort* __restrict__ wT,
    const float* __restrict__ gb, ushort* __restrict__ big,
    ushort* __restrict__ vt, int4 qoff, int4 kvoff, int4 wmods)
{
    __shared__ __align__(16) ushort As[32 * 64];   // 4 KB
    __shared__ __align__(16) ushort Bs[64 * 64];   // 8 KB

    int bm = blockIdx.x * 32;
    int sect = blockIdx.y >> 2, bn = (blockIdx.y & 3) * 64;
    int chunk = bm >> 11, lrow = bm & 2047;
    int wmod = comp(wmods, chunk);
    int asrc = ((sect == 0) ? comp(qoff, chunk) : comp(kvoff, chunk)) + lrow;

    f32x4 acc[1][2];
    acc[0][0] = (f32x4){0.f, 0.f, 0.f, 0.f};
    acc[0][1] = (f32x4){0.f, 0.f, 0.f, 0.f};
    mfma_core<1, 2>(t + (size_t)asrc * 256,
                    wT + (size_t)(sect * 7 + wmod) * 65536 + (size_t)bn * 256,
                    256, 256, 256, As, Bs, acc);

    int wave = threadIdx.x >> 6, lane = threadIdx.x & 63;
    int wr = wave >> 1, wc = wave & 1, lr = lane & 15, q = lane >> 4;
    if (sect == 2) {
#pragma unroll
        for (int fn = 0; fn < 2; ++fn) {
            int col = bn + (wc * 2 + fn) * 16 + lr;
            int hh = col >> 6, ch = col & 63;
            int row0 = lrow + wr * 16 + q * 4;
            ushort4 w;
            w.x = f2bf(acc[0][fn][0]); w.y = f2bf(acc[0][fn][1]);
            w.z = f2bf(acc[0][fn][2]); w.w = f2bf(acc[0][fn][3]);
            *(ushort4*)(vt + ((size_t)((chunk * 4 + hh) * 64 + ch)) * 2048 + row0) = w;
        }
    } else {
#pragma unroll
        for (int rr = 0; rr < 4; ++rr) {
            int rloc = wr * 16 + q * 4 + rr;
#pragma unroll
            for (int fn = 0; fn < 2; ++fn) {
                int col = bn + (wc * 2 + fn) * 16 + lr;
                float v = acc[0][fn][rr];
                if (sect == 3) v = 1.0f / (1.0f + __expf(-(v + gb[wmod * 256 + col])));
                big[(size_t)(chunk * 2048 + lrow + rloc) * 1024 + sect * 256 + col] = f2bf(v);
            }
        }
    }
}

// ---------------------------------------------------------------------------
// Streaming FF up-proj, 32x64 tile, 12 KB LDS. grid (rows/32, 32).
// ---------------------------------------------------------------------------
__global__ __launch_bounds__(256) void ff1_st(
    const ushort* __restrict__ t, const ushort* __restrict__ W1,
    const float* __restrict__ fb1, ushort* __restrict__ outb, int4 fmods)
{
    __shared__ __align__(16) ushort As[32 * 64];   // 4 KB
    __shared__ __align__(16) ushort Bs[64 * 64];   // 8 KB

    int bm = blockIdx.x * 32, bn = blockIdx.y * 64;
    int mod = comp(fmods, bm >> 11);

    f32x4 acc[1][2];
    acc[0][0] = (f32x4){0.f, 0.f, 0.f, 0.f};
    acc[0][1] = (f32x4){0.f, 0.f, 0.f, 0.f};
    mfma_core<1, 2>(t + (size_t)bm * 256,
                    W1 + (size_t)mod * 524288 + (size_t)bn * 256,
                    256, 256, 256, As, Bs, acc);

    int wave = threadIdx.x >> 6, lane = threadIdx.x & 63;
    int wr = wave >> 1, wc = wave & 1, lr = lane & 15, q = lane >> 4;
#pragma unroll
    for (int rr = 0; rr < 4; ++rr) {
        int row = bm + wr * 16 + q * 4 + rr;
#pragma unroll
        for (int fn = 0; fn < 2; ++fn) {
            int col = bn + (wc * 2 + fn) * 16 + lr;
            float v = acc[0][fn][rr] + fb1[mod * 2048 + col];
            outb[(size_t)row * 2048 + col] = f2bf(fmaxf(v, 0.0f));
        }
    }
}

// ---------------------------------------------------------------------------
// Fused banded attention + out-projection (+ optional fused ff-LayerNorm).
// LDS OVERLAY: Ws (32 KB, oproj weight stage) reuses the P/lw/ab region,
// which is dead once the af fragments are loaded to registers. Total LDS
// 50.4 KB -> 32.8 KB: LDS-limited occupancy 3 -> 4 blocks/CU. One extra
// barrier orders all waves' af ds_reads before any Ws staging overwrite.
// ---------------------------------------------------------------------------
__global__ __launch_bounds__(256) void attn_op(
    const ushort* __restrict__ big, const ushort* __restrict__ vt,
    const ushort* __restrict__ woT, const float* __restrict__ aOb,
    float* __restrict__ X, int4 orow, int4 wmods,
    const float* __restrict__ ffg, const float* __restrict__ ffb,
    ushort* __restrict__ tdst, int4 fmods, int fuseLN)
{
    __shared__ __align__(16) ushort smem[16384];     // 32.8 KB total
    ushort* P  = smem;                    // 4*16*72 (dead after PV)
    float*  lw = (float*)(smem + 4608);   // 64 floats (dead after PV)
    ushort* ab = smem + 4736;             // 16*256 swizzled (dead after af load)
    ushort* Ws = smem;                    // 64*256 OVERLAY (live only in oproj)

    int tile = blockIdx.x;
    int chunk = tile >> 7, lt = tile & 127;
    int r0 = lt * 16, s0 = r0 & 1023, seqb = r0 & 1024;
    int t0 = s0 - 16; t0 = t0 < 0 ? 0 : (t0 > SEQ - 48 ? SEQ - 48 : t0);
    int mod = comp(wmods, chunk);
    int h = threadIdx.x >> 6, lane = threadIdx.x & 63;
    int lr = lane & 15, q = lane >> 4;
    size_t rowbase = (size_t)(chunk * 2048 + r0);
    size_t kvbase  = (size_t)(chunk * 2048 + seqb + t0);

    // S = Q K^T
    short8 aq[2];
#pragma unroll
    for (int s = 0; s < 2; ++s)
        aq[s] = *(const short8*)(big + (rowbase + lr) * 1024 + h * 64 + s * 32 + q * 8);
    f32x4 sc[3];
#pragma unroll
    for (int kt = 0; kt < 3; ++kt) {
        sc[kt] = (f32x4){0.f, 0.f, 0.f, 0.f};
        const ushort* kr = big + (kvbase + kt * 16 + lr) * 1024 + 256 + h * 64;
#pragma unroll
        for (int s = 0; s < 2; ++s)
            sc[kt] = __builtin_amdgcn_mfma_f32_16x16x32_bf16(
                aq[s], *(const short8*)(kr + s * 32 + q * 8), sc[kt], 0, 0, 0);
    }
    // zero P pad cols 48..63
    { int zr = lane >> 2, zc = 48 + (lane & 3) * 4;
      *(ushort4*)(P + h * 1152 + zr * 72 + zc) = (ushort4){0, 0, 0, 0}; }
    // mask + softmax (rows=queries, cols=keys)
    float pv[3][4], lsum[4];
#pragma unroll
    for (int r = 0; r < 4; ++r) {
        int sq = s0 + q * 4 + r;
#pragma unroll
        for (int kt = 0; kt < 3; ++kt) {
            int tt = t0 + kt * 16 + lr;
            int d = tt - sq;
            pv[kt][r] = (d <= WIN && d >= -WIN) ? sc[kt][r] * 0.125f : -1e30f;
        }
        float m = fmaxf(pv[0][r], fmaxf(pv[1][r], pv[2][r]));
#pragma unroll
        for (int off = 1; off <= 8; off <<= 1) m = fmaxf(m, __shfl_xor(m, off));
        float l = 0.f;
#pragma unroll
        for (int kt = 0; kt < 3; ++kt) { float p = __expf(pv[kt][r] - m); pv[kt][r] = p; l += p; }
#pragma unroll
        for (int off = 1; off <= 8; off <<= 1) l += __shfl_xor(l, off);
        lsum[r] = l;
    }
#pragma unroll
    for (int r = 0; r < 4; ++r)
#pragma unroll
        for (int kt = 0; kt < 3; ++kt)
            P[h * 1152 + (q * 4 + r) * 72 + kt * 16 + lr] = f2bf(pv[kt][r]);
    if (lr == 0) {
#pragma unroll
        for (int r = 0; r < 4; ++r) lw[h * 16 + q * 4 + r] = lsum[r];
    }
    __syncthreads();

    // O = P @ V -> D[query][ch]; apply 1/l and G; store swizzled bf16 to ab
#pragma unroll
    for (int ct = 0; ct < 4; ++ct) {
        f32x4 o = (f32x4){0.f, 0.f, 0.f, 0.f};
#pragma unroll
        for (int s = 0; s < 2; ++s) {
            short8 av = *(const short8*)(vt +
                ((size_t)((chunk * 4 + h) * 64 + ct * 16 + lr)) * 2048 +
                seqb + t0 + s * 32 + q * 8);
            short8 bp = *(const short8*)(P + h * 1152 + lr * 72 + s * 32 + q * 8);
            o = __builtin_amdgcn_mfma_f32_16x16x32_bf16(bp, av, o, 0, 0, 0);
        }
        int ch = h * 64 + ct * 16 + lr;
#pragma unroll
        for (int r = 0; r < 4; ++r) {
            int qr = q * 4 + r;
            float gv = bf2f(big[(rowbase + qr) * 1024 + 768 + ch]);
            float val = o[r] * (1.0f / lw[h * 16 + qr]) * gv;
            ab[qr * 256 + ((((ch >> 3) ^ (qr & 7)) << 3) | (ch & 7))] = f2bf(val);
        }
    }
    __syncthreads();   // ab complete (all waves)

    // oproj: load af fragments to registers, THEN Ws may overlay ab.
    short8 af[8];
#pragma unroll
    for (int s = 0; s < 8; ++s)
        af[s] = *(const short8*)(ab + lr * 256 + (((s * 4 + q) ^ (lr & 7)) << 3));
    __syncthreads();   // all waves' af ds_reads drained before Ws overwrite
    int xrow0 = comp(orow, chunk) + r0;
    const ushort* Wo = woT + (size_t)mod * 65536;
    float accs[4][4];
#pragma unroll
    for (int oc = 0; oc < 4; ++oc) {
        stage_fk(Wo + (size_t)(oc * 64) * 256, Ws, h, lane);
        __syncthreads();
        f32x4 acc = (f32x4){0.f, 0.f, 0.f, 0.f};
        int wrow = h * 16 + lr;
#pragma unroll
        for (int s = 0; s < 8; ++s) {
            short8 bf_ = *(const short8*)(Ws + wrow * 256 + (((s * 4 + q) ^ (wrow & 7)) << 3));
            acc = __builtin_amdgcn_mfma_f32_16x16x32_bf16(af[s], bf_, acc, 0, 0, 0);
        }
#pragma unroll
        for (int r = 0; r < 4; ++r) accs[oc][r] = acc[r];
        if (oc < 3) __syncthreads();   // last barrier redundant: Ws not restaged
    }

    if (!fuseLN) {
#pragma unroll
        for (int oc = 0; oc < 4; ++oc) {
            int col = oc * 64 + h * 16 + lr;
            float bias = aOb[mod * 256 + col];
#pragma unroll
            for (int r = 0; r < 4; ++r)
                atomicAdd(X + (size_t)(xrow0 + q * 4 + r) * 256 + col, accs[oc][r] + bias);
        }
        return;
    }

    // -------- fused residual + ff-LayerNorm (sole-writer rows) --------
    float xv[4][4];            // [oc][r]
    float s1[4] = {0.f, 0.f, 0.f, 0.f}, s2[4] = {0.f, 0.f, 0.f, 0.f};
#pragma unroll
    for (int oc = 0; oc < 4; ++oc) {
        int col = oc * 64 + h * 16 + lr;
        float bias = aOb[mod * 256 + col];
#pragma unroll
        for (int r = 0; r < 4; ++r) {
            size_t idx = (size_t)(xrow0 + q * 4 + r) * 256 + col;
            float v = X[idx] + accs[oc][r] + bias;
            X[idx] = v;
            xv[oc][r] = v;
            s1[r] += v;
            s2[r] += v * v;
        }
    }
#pragma unroll
    for (int off = 1; off <= 8; off <<= 1) {
#pragma unroll
        for (int r = 0; r < 4; ++r) {
            s1[r] += __shfl_xor(s1[r], off);
            s2[r] += __shfl_xor(s2[r], off);
        }
    }
    float* sred = (float*)smem;  // overlays Ws row 0 (dead after barrier below)
    __syncthreads();             // all waves past Ws reads before sred reuse
    if (lr == 0) {
#pragma unroll
        for (int r = 0; r < 4; ++r) {
            sred[(q * 4 + r) * 8 + h * 2 + 0] = s1[r];
            sred[(q * 4 + r) * 8 + h * 2 + 1] = s2[r];
        }
    }
    __syncthreads();
    int fmod = comp(fmods, chunk);
#pragma unroll
    for (int r = 0; r < 4; ++r) {
        int rw = q * 4 + r;
        float t1 = sred[rw * 8 + 0] + sred[rw * 8 + 2] + sred[rw * 8 + 4] + sred[rw * 8 + 6];
        float t2 = sred[rw * 8 + 1] + sred[rw * 8 + 3] + sred[rw * 8 + 5] + sred[rw * 8 + 7];
        float mean = t1 * (1.0f / 256.0f);
        float var  = t2 * (1.0f / 256.0f) - mean * mean;
        float rstd = rsqrtf(var + 1e-5f);
#pragma unroll
        for (int oc = 0; oc < 4; ++oc) {
            int col = oc * 64 + h * 16 + lr;
            tdst[(size_t)(xrow0 + rw) * 256 + col] =
                f2bf((xv[oc][r] - mean) * rstd * ffg[fmod * 256 + col] + ffb[fmod * 256 + col]);
        }
    }
}

// ---------------------------------------------------------------------------
// Orchestration
// ---------------------------------------------------------------------------
extern "C" void kernel_launch(void* const* d_in, const int* in_sizes, int n_in,
                              void* d_out, int out_size, void* d_ws, size_t ws_size,
                              hipStream_t stream)
{
    const float* inL   = (const float*)d_in[0];
    const float* inN   = (const float*)d_in[1];
    const float* inO   = (const float*)d_in[2];
    const float* aWq   = (const float*)d_in[4];
    const float* aWk   = (const float*)d_in[5];
    const float* aWv   = (const float*)d_in[6];
    const float* aGw   = (const float*)d_in[7];
    const float* aGb   = (const float*)d_in[8];
    const float* aOw   = (const float*)d_in[9];
    const float* aOb   = (const float*)d_in[10];
    const float* ln_g  = (const float*)d_in[11];
    const float* ln_b  = (const float*)d_in[12];
    const float* ff_g  = (const float*)d_in[13];
    const float* ff_b  = (const float*)d_in[14];
    const float* ff_w1 = (const float*)d_in[15];
    const float* ff_b1 = (const float*)d_in[16];
    const float* ff_w2 = (const float*)d_in[17];
    const float* ff_b2 = (const float*)d_in[18];

    const size_t TD = (size_t)2048 * DIM;
    float* X = (float*)d_out;               // [6144][256]: L | N | O

    ushort* ws  = (ushort*)d_ws;
    ushort* wT  = ws;                       // 35 x 65536 (q0..6,k,v,g,o)
    ushort* woT = wT + 28 * 65536;          // o-proj weights (within wT)
    ushort* w1T = wT + 35 * 65536;          // 6x [2048][256]
    ushort* w2T = w1T + 6 * 524288;         // 6x [256][2048]
    ushort* t   = w2T + 6 * 524288;         // [6144][256] LN outputs
    ushort* big = t + 6144 * 256;           // QKVG [6144][1024] / FF hidden
    ushort* vt  = big + (size_t)6144 * 2048;// V^T: 3 chunks x 4h x 64ch x 2048

    transpose_qkv<<<dim3(8, 8, 35), 256, 0, stream>>>(aWq, aWk, aWv, aGw, aOw, wT);
    transpose_bf16<<<dim3(64, 8, 6), 256, 0, stream>>>(ff_w1, w1T, 256, 2048);
    transpose_bf16<<<dim3(8, 64, 6), 256, 0, stream>>>(ff_w2, w2T, 2048, 256);

    hipMemcpyAsync(X,          inL, TD * sizeof(float), hipMemcpyDeviceToDevice, stream);
    hipMemcpyAsync(X + TD,     inN, TD * sizeof(float), hipMemcpyDeviceToDevice, stream);
    hipMemcpyAsync(X + 2 * TD, inO, TD * sizeof(float), hipMemcpyDeviceToDevice, stream);

    auto ffblock = [&](int nrows, int rowOff, int4 fmods, bool needLN) {
        if (needLN)
            ln_bat<<<dim3(nrows / 4), 256, 0, stream>>>(X, t, ff_g, ff_b, rowOff, fmods);
        ff1_st<<<dim3(nrows / 32, 32), 256, 0, stream>>>(
            t + (size_t)rowOff * 256, w1T, ff_b1, big, fmods);
        gemm_split<1, 2><<<dim3(nrows / 32, 4, 4), 256, 0, stream>>>(
            big, w2T, ff_b2, X + (size_t)rowOff * 256, 256, 2048, 512, fmods);
    };

    for (int it = 0; it < 2; ++it) {
        // ---- Phase A: self-attention + FF on L,N,O (mods 0,1,2) ----
        ln_bat<<<dim3(1536), 256, 0, stream>>>(X, t, ln_g, ln_b, 0, make_int4(0, 1, 2, 0));
        qkvg_st<<<dim3(192, 16), 256, 0, stream>>>(
            t, wT, aGb, big, vt,
            make_int4(0, 2048, 4096, 0), make_int4(0, 2048, 4096, 0),
            make_int4(0, 1, 2, 0));
        attn_op<<<dim3(384), 256, 0, stream>>>(
            big, vt, woT, aOb, X, make_int4(0, 2048, 4096, 0), make_int4(0, 1, 2, 0),
            ff_g, ff_b, t, make_int4(0, 1, 2, 0), 1);
        ffblock(6144, 0, make_int4(0, 1, 2, 0), false);

        // ---- Phase B: L,N cross-attend tO (mods 3,4; ln by src chunk 4,5,3) ----
        ln_bat<<<dim3(1536), 256, 0, stream>>>(X, t, ln_g, ln_b, 0, make_int4(4, 5, 3, 0));
        qkvg_st<<<dim3(128, 16), 256, 0, stream>>>(
            t, wT, aGb, big, vt,
            make_int4(0, 2048, 0, 0), make_int4(4096, 4096, 0, 0),
            make_int4(3, 4, 0, 0));
        attn_op<<<dim3(256), 256, 0, stream>>>(
            big, vt, woT, aOb, X, make_int4(0, 2048, 0, 0), make_int4(3, 4, 0, 0),
            ff_g, ff_b, t, make_int4(3, 4, 0, 0), 1);
        ffblock(4096, 0, make_int4(3, 4, 0, 0), false);

        // ---- Phase C: O += att5(tO,tN) + att6(tO,tL); FF(5,O) ----
        ln_bat<<<dim3(1536), 256, 0, stream>>>(X, t, ln_g, ln_b, 0, make_int4(6, 7, 8, 0));
        qkvg_st<<<dim3(128, 16), 256, 0, stream>>>(
            t, wT, aGb, big, vt,
            make_int4(4096, 4096, 0, 0), make_int4(2048, 0, 0, 0),
            make_int4(5, 6, 0, 0));
        attn_op<<<dim3(256), 256, 0, stream>>>(
            big, vt, woT, aOb, X, make_int4(4096, 4096, 0, 0), make_int4(5, 6, 0, 0),
            ff_g, ff_b, t, make_int4(5, 0, 0, 0), 0);
        ffblock(2048, 4096, make_int4(5, 0, 0, 0), true);
    }
}